// Round 7
// baseline (486.861 us; speedup 1.0000x reference)
//
#include <hip/hip_runtime.h>
#include <math.h>

constexpr int IN_F = 128;
constexpr int HID  = 64;
constexpr int OUT_F = 10;
constexpr int NG   = 256;
constexpr int BSH  = 7;            // 128 nodes per bucket
constexpr int BNODES = 1 << BSH;
constexpr int CAP  = 3072;         // per-bucket edge capacity (mean ~2046, +22 sigma)

// NOTE: packing assumes N < 2^20 (src id in low 20 bits, local col in bits 20..26).

// ---- bf16 helpers (RNE) ----
__device__ __forceinline__ unsigned short f2bf(float f) {
    unsigned u = __float_as_uint(f);
    u += 0x7FFFu + ((u >> 16) & 1u);
    return (unsigned short)(u >> 16);
}
__device__ __forceinline__ float lo16(unsigned u) { return __uint_as_float(u << 16); }
__device__ __forceinline__ float hi16(unsigned u) { return __uint_as_float(u & 0xFFFF0000u); }
__device__ __forceinline__ float bf2f(unsigned short s) { return __uint_as_float((unsigned)s << 16); }

__device__ __forceinline__ void acc8(float* a, uint4 v) {
    a[0] += lo16(v.x); a[1] += hi16(v.x);
    a[2] += lo16(v.y); a[3] += hi16(v.y);
    a[4] += lo16(v.z); a[5] += hi16(v.z);
    a[6] += lo16(v.w); a[7] += hi16(v.w);
}

// ---- int32/int64 detection ----
__global__ void k_detect(const unsigned int* w, int nwords, int* flag) {
    __shared__ int nz;
    if (threadIdx.x == 0) nz = 0;
    __syncthreads();
    int seen = 0;
    for (int i = 1 + 2 * (int)threadIdx.x; i < nwords; i += 2 * (int)blockDim.x)
        if (w[i] != 0u) seen = 1;
    if (seen) atomicOr(&nz, 1);
    __syncthreads();
    if (threadIdx.x == 0) *flag = (nz == 0) ? 1 : 0;   // 1 => int64
}

__device__ __forceinline__ int ld_idx(const void* p, long long i, int is64) {
    return is64 ? (int)((const long long*)p)[i] : ((const int*)p)[i];
}

// ---- pass 1: bucket edges by col>>BSH, append packed (src | lc<<20) ----
__global__ void k_bucket(const void* eidx, const int* f64, int E,
                         int* gcur, unsigned* bucketed) {
    int e = blockIdx.x * blockDim.x + threadIdx.x;
    if (e >= E) return;
    int is64 = *f64;
    int r = ld_idx(eidx, e, is64);
    int c = ld_idx(eidx, (long long)E + e, is64);
    int b = c >> BSH;
    int pos = atomicAdd(&gcur[b], 1);
    if (pos < CAP)
        bucketed[(long long)b * CAP + pos] =
            (unsigned)r | ((unsigned)(c & (BNODES - 1)) << 20);
}

// ---- scan bucket counts -> bucket edge offsets ----
__global__ __launch_bounds__(512) void k_bscan(const int* __restrict__ gcur,
                                               int* __restrict__ gofs, int nbuk,
                                               int* rowptr, int N, int E) {
    __shared__ int tot[512];
    int tid = threadIdx.x;
    int chunk = (nbuk + 511) / 512;
    int st = tid * chunk, en = min(st + chunk, nbuk);
    int s = 0;
    for (int i = st; i < en; ++i) s += min(gcur[i], CAP);
    tot[tid] = s;
    __syncthreads();
    for (int off = 1; off < 512; off <<= 1) {
        int a = (tid >= off) ? tot[tid - off] : 0;
        __syncthreads();
        tot[tid] += a;
        __syncthreads();
    }
    int run = tot[tid] - s;
    for (int i = st; i < en; ++i) { gofs[i] = run; run += min(gcur[i], CAP); }
    if (tid == 0) rowptr[N] = E;
}

// ---- pass 2: per-bucket local counting sort -> rowptr, dinv, csr_src ----
__global__ __launch_bounds__(256) void k_bfill(const int* __restrict__ gcur,
                                               const int* __restrict__ gofs,
                                               const unsigned* __restrict__ bucketed,
                                               int* __restrict__ rowptr,
                                               float* __restrict__ dinv,
                                               int* __restrict__ csr_src, int N) {
    __shared__ int lhist[BNODES], lrp[BNODES], lcur[BNODES];
    __shared__ int stage[CAP];
    int b = blockIdx.x;
    int cnt = min(gcur[b], CAP);
    int base = gofs[b];
    int nb0 = b << BSH;
    int tid = threadIdx.x;
    const unsigned* bk = bucketed + (long long)b * CAP;
    if (tid < BNODES) { lhist[tid] = 0; lcur[tid] = 0; }
    __syncthreads();
    for (int t = tid; t < cnt; t += 256)
        atomicAdd(&lhist[bk[t] >> 20], 1);
    __syncthreads();
    if (tid == 0) {
        int run = 0;
        for (int i = 0; i < BNODES; ++i) { lrp[i] = run; run += lhist[i]; }
    }
    __syncthreads();
    if (tid < BNODES) {
        int node = nb0 + tid;
        if (node < N) {
            rowptr[node] = base + lrp[tid];
            dinv[node] = rsqrtf((float)lhist[tid] + 1.0f);
        }
    }
    for (int t = tid; t < cnt; t += 256) {
        unsigned v = bk[t];
        int lc = v >> 20;
        int p = atomicAdd(&lcur[lc], 1);
        stage[lrp[lc] + p] = (int)(v & 0xFFFFFu);
    }
    __syncthreads();
    for (int t = tid; t < cnt; t += 256) csr_src[base + t] = stage[t];
}

// ---- lin1: h0 = relu(x@w1+b1) raw bf16; hs0 = h0*dinv bf16 ----
constexpr int NB = 16;
__global__ __launch_bounds__(256) void k_lin1(const float* __restrict__ x,
                                              const float* __restrict__ w1,
                                              const float* __restrict__ b1,
                                              const float* __restrict__ dinv,
                                              unsigned short* __restrict__ h0,
                                              unsigned short* __restrict__ hs0, int N) {
    __shared__ float xs[NB][IN_F];
    int nb0 = blockIdx.x * NB;
    for (int t = threadIdx.x; t < NB * (IN_F / 4); t += 256) {
        int n = t >> 5, k4 = t & 31;
        int gn = nb0 + n;
        float4 v = make_float4(0.f, 0.f, 0.f, 0.f);
        if (gn < N) v = ((const float4*)x)[(long long)gn * (IN_F / 4) + k4];
        *(float4*)&xs[n][k4 * 4] = v;
    }
    __syncthreads();
    int wv = threadIdx.x >> 6;
    int c  = threadIdx.x & 63;
    int n0 = wv * 4;
    float bias = b1[c];
    float a0 = bias, a1 = bias, a2 = bias, a3 = bias;
    #pragma unroll 4
    for (int k = 0; k < IN_F; k += 4) {
        float w_0 = w1[(k + 0) * HID + c];
        float w_1 = w1[(k + 1) * HID + c];
        float w_2 = w1[(k + 2) * HID + c];
        float w_3 = w1[(k + 3) * HID + c];
        float4 x0 = *(float4*)&xs[n0 + 0][k];
        float4 x1 = *(float4*)&xs[n0 + 1][k];
        float4 x2 = *(float4*)&xs[n0 + 2][k];
        float4 x3 = *(float4*)&xs[n0 + 3][k];
        a0 = fmaf(x0.x, w_0, a0); a0 = fmaf(x0.y, w_1, a0);
        a0 = fmaf(x0.z, w_2, a0); a0 = fmaf(x0.w, w_3, a0);
        a1 = fmaf(x1.x, w_0, a1); a1 = fmaf(x1.y, w_1, a1);
        a1 = fmaf(x1.z, w_2, a1); a1 = fmaf(x1.w, w_3, a1);
        a2 = fmaf(x2.x, w_0, a2); a2 = fmaf(x2.y, w_1, a2);
        a2 = fmaf(x2.z, w_2, a2); a2 = fmaf(x2.w, w_3, a2);
        a3 = fmaf(x3.x, w_0, a3); a3 = fmaf(x3.y, w_1, a3);
        a3 = fmaf(x3.z, w_2, a3); a3 = fmaf(x3.w, w_3, a3);
    }
    float acc[4] = {a0, a1, a2, a3};
    #pragma unroll
    for (int n = 0; n < 4; ++n) {
        int gn = nb0 + n0 + n;
        if (gn < N) {
            float r = fmaxf(acc[n], 0.f);
            h0 [(long long)gn * HID + c] = f2bf(r);
            hs0[(long long)gn * HID + c] = f2bf(r * dinv[gn]);
        }
    }
}

// ---- fused GCN2 layer (unchanged from round 6) ----
__global__ __launch_bounds__(256) void k_layer(const int* __restrict__ rowptr,
                                               const int* __restrict__ csr_src,
                                               const float* __restrict__ dinv,
                                               const unsigned short* __restrict__ hs_in,
                                               const unsigned short* __restrict__ h0,
                                               const float* __restrict__ W,
                                               float beta, int scale_out,
                                               unsigned short* __restrict__ h_out, int N) {
    __shared__ float ss[4][HID];
    const uint4* hin4 = (const uint4*)hs_in;
    const uint4* h04  = (const uint4*)h0;
    int wv = threadIdx.x >> 6;
    int l  = threadIdx.x & 63;
    int q  = l >> 3;
    int m  = l & 7;
    int node = blockIdx.x * 4 + wv;

    if (node < N) {
        float a[8] = {0.f, 0.f, 0.f, 0.f, 0.f, 0.f, 0.f, 0.f};
        int e0 = rowptr[node], e1 = rowptr[node + 1];
        int e = e0;
        for (; e + 16 <= e1; e += 16) {
            int r0 = csr_src[e + q];
            int r1 = csr_src[e + 8 + q];
            uint4 v0 = hin4[(long long)r0 * 8 + m];
            uint4 v1 = hin4[(long long)r1 * 8 + m];
            acc8(a, v0);
            acc8(a, v1);
        }
        if (e < e1) {
            int ee0 = e + q, ee1 = e + 8 + q;
            if (ee0 < e1) {
                int r = csr_src[ee0];
                uint4 v = hin4[(long long)r * 8 + m];
                acc8(a, v);
            }
            if (ee1 < e1) {
                int r = csr_src[ee1];
                uint4 v = hin4[(long long)r * 8 + m];
                acc8(a, v);
            }
        }
        #pragma unroll
        for (int off = 8; off <= 32; off <<= 1) {
            #pragma unroll
            for (int j = 0; j < 8; ++j) a[j] += __shfl_xor(a[j], off, 64);
        }
        if (q == 0) {
            float di = dinv[node];
            uint4 hv = hin4[(long long)node * 8 + m];
            uint4 rv = h04 [(long long)node * 8 + m];
            float hs[8] = {lo16(hv.x), hi16(hv.x), lo16(hv.y), hi16(hv.y),
                           lo16(hv.z), hi16(hv.z), lo16(hv.w), hi16(hv.w)};
            float r0[8] = {lo16(rv.x), hi16(rv.x), lo16(rv.y), hi16(rv.y),
                           lo16(rv.z), hi16(rv.z), lo16(rv.w), hi16(rv.w)};
            float s[8];
            #pragma unroll
            for (int j = 0; j < 8; ++j)
                s[j] = fmaf(0.9f * di, a[j] + hs[j], 0.1f * r0[j]);
            *(float4*)&ss[wv][8 * m]     = make_float4(s[0], s[1], s[2], s[3]);
            *(float4*)&ss[wv][8 * m + 4] = make_float4(s[4], s[5], s[6], s[7]);
        }
    }
    __syncthreads();
    if (node >= N) return;
    int c = l;
    float s = ss[wv][c];
    float mm = 0.f;
    const float4* ssv = (const float4*)&ss[wv][0];
    #pragma unroll
    for (int k4 = 0; k4 < 16; ++k4) {
        float4 sv = ssv[k4];
        mm = fmaf(sv.x, W[(4 * k4 + 0) * HID + c], mm);
        mm = fmaf(sv.y, W[(4 * k4 + 1) * HID + c], mm);
        mm = fmaf(sv.z, W[(4 * k4 + 2) * HID + c], mm);
        mm = fmaf(sv.w, W[(4 * k4 + 3) * HID + c], mm);
    }
    float v = fmaxf(s + beta * (mm - s), 0.f);
    if (scale_out) v *= dinv[node];
    h_out[(long long)node * HID + c] = f2bf(v);
}

// ---- pooling: batch SORTED -> register-accumulate, flush on boundary ----
constexpr int POOL_CHUNK = 256;
__global__ __launch_bounds__(256) void k_pool(const unsigned short* __restrict__ h,
                                              const void* batch, const int* f64,
                                              float* psum, float* pcnt, int N) {
    int c = threadIdx.x & 63;
    int g = threadIdx.x >> 6;
    int n0 = blockIdx.x * POOL_CHUNK;
    int nend = min(n0 + POOL_CHUNK, N);
    int is64 = *f64;
    float sum = 0.f;
    int cnt = 0, curb = -1;
    for (int n = n0 + g; n < nend; n += 4) {
        int b = ld_idx(batch, n, is64);
        if (b != curb) {
            if (curb >= 0) {
                atomicAdd(&psum[(long long)curb * HID + c], sum);
                if (c == 0) atomicAdd(&pcnt[curb], (float)cnt);
            }
            curb = b; sum = 0.f; cnt = 0;
        }
        sum += bf2f(h[(long long)n * HID + c]);
        cnt++;
    }
    if (curb >= 0) {
        atomicAdd(&psum[(long long)curb * HID + c], sum);
        if (c == 0) atomicAdd(&pcnt[curb], (float)cnt);
    }
}

// ---- out[g] = (psum[g]/max(cnt,1)) @ w2 + b2 ----
__global__ void k_out(const float* __restrict__ psum, const float* __restrict__ pcnt,
                      const float* __restrict__ w2, const float* __restrict__ b2,
                      float* __restrict__ out) {
    int g = blockIdx.x;
    int tid = threadIdx.x;   // 64
    __shared__ float pr[HID];
    float cnt = fmaxf(pcnt[g], 1.0f);
    pr[tid] = psum[(long long)g * HID + tid] / cnt;
    __syncthreads();
    if (tid < OUT_F) {
        float acc = b2[tid];
        #pragma unroll
        for (int k = 0; k < HID; ++k)
            acc = fmaf(pr[k], w2[k * OUT_F + tid], acc);
        out[g * OUT_F + tid] = acc;
    }
}

static inline size_t align256(size_t x) { return (x + 255) & ~(size_t)255; }

extern "C" void kernel_launch(void* const* d_in, const int* in_sizes, int n_in,
                              void* d_out, int out_size, void* d_ws, size_t ws_size,
                              hipStream_t stream) {
    const float* x     = (const float*)d_in[0];
    const void*  eidx  = d_in[1];
    const void*  batch = d_in[2];
    const float* w1    = (const float*)d_in[3];
    const float* b1    = (const float*)d_in[4];
    const float* convw = (const float*)d_in[5];
    const float* w2    = (const float*)d_in[6];
    const float* b2    = (const float*)d_in[7];
    float* out = (float*)d_out;

    int N = in_sizes[0] / IN_F;
    int E = in_sizes[1] / 2;
    int nbuk = (N + BNODES - 1) >> BSH;

    char* ws = (char*)d_ws;
    float* dinv    = (float*)ws;                ws += align256((size_t)N * 4);
    unsigned short* h0  = (unsigned short*)ws;  ws += align256((size_t)N * HID * 2);
    unsigned short* hs0 = (unsigned short*)ws;  ws += align256((size_t)N * HID * 2);
    unsigned short* hb  = (unsigned short*)ws;  ws += align256((size_t)N * HID * 2);
    float* psum    = (float*)ws;                ws += align256((size_t)NG * HID * 4);
    float* pcnt    = (float*)ws;                ws += align256((size_t)NG * 4);
    int*   rowptr  = (int*)ws;                  ws += align256((size_t)(N + 1) * 4);
    int*   csr_src = (int*)ws;                  ws += align256((size_t)E * 4);
    int*   gcur    = (int*)ws;                  ws += align256((size_t)nbuk * 4);
    int*   gofs    = (int*)ws;                  ws += align256((size_t)(nbuk + 1) * 4);
    unsigned* bucketed = (unsigned*)ws;         ws += align256((size_t)nbuk * CAP * 4);
    int*   flag    = (int*)ws;

    // 1. dtype detect
    k_detect<<<1, 256, 0, stream>>>((const unsigned int*)eidx, 4096, flag);

    // 2. bucketed CSR build (+ rowptr, dinv)
    hipMemsetAsync(gcur, 0, (size_t)nbuk * 4, stream);
    k_bucket<<<(E + 255) / 256, 256, 0, stream>>>(eidx, flag, E, gcur, bucketed);
    k_bscan<<<1, 512, 0, stream>>>(gcur, gofs, nbuk, rowptr, N, E);
    k_bfill<<<nbuk, 256, 0, stream>>>(gcur, gofs, bucketed, rowptr, dinv, csr_src, N);

    // 3. lin1 -> h0 (raw) + hs0 (scaled)
    k_lin1<<<(N + NB - 1) / NB, 256, 0, stream>>>(x, w1, b1, dinv, h0, hs0, N);

    // 4. three fused GCN2 layers: hs0 -> hb -> hs0 -> hb(raw)
    int nlb = (N + 3) / 4;
    float beta0 = logf(0.5f / 1.0f + 1.0f);
    float beta1 = logf(0.5f / 2.0f + 1.0f);
    float beta2 = logf(0.5f / 3.0f + 1.0f);
    k_layer<<<nlb, 256, 0, stream>>>(rowptr, csr_src, dinv, hs0, h0,
                                     convw + 0 * HID * HID, beta0, 1, hb, N);
    k_layer<<<nlb, 256, 0, stream>>>(rowptr, csr_src, dinv, hb, h0,
                                     convw + 1 * HID * HID, beta1, 1, hs0, N);
    k_layer<<<nlb, 256, 0, stream>>>(rowptr, csr_src, dinv, hs0, h0,
                                     convw + 2 * HID * HID, beta2, 0, hb, N);

    // 5. pooling + final linear (raw h is hb)
    hipMemsetAsync(psum, 0, ((size_t)NG * HID + NG) * 4, stream);
    k_pool<<<(N + POOL_CHUNK - 1) / POOL_CHUNK, 256, 0, stream>>>(hb, batch, flag,
                                                                  psum, pcnt, N);
    k_out<<<NG, 64, 0, stream>>>(psum, pcnt, w2, b2, out);
}

// Round 8
// 251.863 us; speedup vs baseline: 1.9330x; 1.9330x over previous
//
#include <hip/hip_runtime.h>
#include <math.h>

constexpr int IN_F = 128;
constexpr int HID  = 64;
constexpr int OUT_F = 10;
constexpr int NG   = 256;
constexpr int BSH  = 7;            // 128 nodes per bucket
constexpr int BNODES = 1 << BSH;
constexpr int SLICES = 32;         // sub-counters per bucket (kills atomic contention)
constexpr int SCAP = 128;          // per-(bucket,slice) capacity; mean ~64, +8 sigma
constexpr int SCAPSH = 7;

// NOTE: packing assumes N < 2^20 (src id in low 20 bits, local col in bits 20..26).

// ---- bf16 helpers (RNE) ----
__device__ __forceinline__ unsigned short f2bf(float f) {
    unsigned u = __float_as_uint(f);
    u += 0x7FFFu + ((u >> 16) & 1u);
    return (unsigned short)(u >> 16);
}
__device__ __forceinline__ float lo16(unsigned u) { return __uint_as_float(u << 16); }
__device__ __forceinline__ float hi16(unsigned u) { return __uint_as_float(u & 0xFFFF0000u); }
__device__ __forceinline__ float bf2f(unsigned short s) { return __uint_as_float((unsigned)s << 16); }

__device__ __forceinline__ void acc8(float* a, uint4 v) {
    a[0] += lo16(v.x); a[1] += hi16(v.x);
    a[2] += lo16(v.y); a[3] += hi16(v.y);
    a[4] += lo16(v.z); a[5] += hi16(v.z);
    a[6] += lo16(v.w); a[7] += hi16(v.w);
}

// ---- int32/int64 detection ----
__global__ void k_detect(const unsigned int* w, int nwords, int* flag) {
    __shared__ int nz;
    if (threadIdx.x == 0) nz = 0;
    __syncthreads();
    int seen = 0;
    for (int i = 1 + 2 * (int)threadIdx.x; i < nwords; i += 2 * (int)blockDim.x)
        if (w[i] != 0u) seen = 1;
    if (seen) atomicOr(&nz, 1);
    __syncthreads();
    if (threadIdx.x == 0) *flag = (nz == 0) ? 1 : 0;   // 1 => int64
}

__device__ __forceinline__ int ld_idx(const void* p, long long i, int is64) {
    return is64 ? (int)((const long long*)p)[i] : ((const int*)p)[i];
}

// ---- pass 1: bucket edges by col>>BSH into 32-sliced regions ----
__global__ void k_bucket(const void* eidx, const int* f64, int E,
                         int* gcur, unsigned* bucketed) {
    int e = blockIdx.x * blockDim.x + threadIdx.x;
    if (e >= E) return;
    int is64 = *f64;
    int r = ld_idx(eidx, e, is64);
    int c = ld_idx(eidx, (long long)E + e, is64);
    int b = c >> BSH;
    int s = (e >> 8) & (SLICES - 1);          // per-256-edge-block slice
    int reg = b * SLICES + s;
    int pos = atomicAdd(&gcur[reg], 1);
    if (pos < SCAP)
        bucketed[((long long)reg << SCAPSH) + pos] =
            (unsigned)r | ((unsigned)(c & (BNODES - 1)) << 20);
}

// ---- scan per-bucket totals (sum of slice counts) -> bucket edge offsets ----
__global__ __launch_bounds__(512) void k_bscan(const int* __restrict__ gcur,
                                               int* __restrict__ gofs, int nbuk,
                                               int* rowptr, int N) {
    __shared__ int tot[512];
    int tid = threadIdx.x;
    int chunk = (nbuk + 511) / 512;
    int st = tid * chunk, en = min(st + chunk, nbuk);
    int s = 0;
    for (int i = st; i < en; ++i) {
        int t = 0;
        for (int k = 0; k < SLICES; ++k) t += min(gcur[i * SLICES + k], SCAP);
        s += t;
    }
    tot[tid] = s;
    __syncthreads();
    for (int off = 1; off < 512; off <<= 1) {
        int a = (tid >= off) ? tot[tid - off] : 0;
        __syncthreads();
        tot[tid] += a;
        __syncthreads();
    }
    int run = tot[tid] - s;
    for (int i = st; i < en; ++i) {
        gofs[i] = run;
        int t = 0;
        for (int k = 0; k < SLICES; ++k) t += min(gcur[i * SLICES + k], SCAP);
        run += t;
    }
    if (tid == 511) rowptr[N] = tot[511];   // grand total (== E unless overflow)
}

// ---- pass 2: per-bucket local counting sort -> rowptr, dinv, csr_src ----
__global__ __launch_bounds__(256) void k_bfill(const int* __restrict__ gcur,
                                               const int* __restrict__ gofs,
                                               const unsigned* __restrict__ bucketed,
                                               int* __restrict__ rowptr,
                                               float* __restrict__ dinv,
                                               int* __restrict__ csr_src, int N) {
    __shared__ int lcnt[SLICES];
    __shared__ int lhist[BNODES], lrp[BNODES], lcur[BNODES];
    __shared__ int stage[SLICES * SCAP];
    int b = blockIdx.x;
    int base = gofs[b];
    int nb0 = b << BSH;
    int tid = threadIdx.x;
    const unsigned* bk = bucketed + ((long long)(b * SLICES) << SCAPSH);
    if (tid < SLICES) lcnt[tid] = min(gcur[b * SLICES + tid], SCAP);
    if (tid < BNODES) { lhist[tid] = 0; lcur[tid] = 0; }
    __syncthreads();
    // histogram over valid slots
    for (int t = tid; t < SLICES * SCAP; t += 256) {
        int s = t >> SCAPSH, p = t & (SCAP - 1);
        if (p < lcnt[s]) atomicAdd(&lhist[bk[t] >> 20], 1);
    }
    __syncthreads();
    // parallel exclusive scan of lhist (128 elems, Hillis-Steele in LDS)
    if (tid < BNODES) lrp[tid] = lhist[tid];
    __syncthreads();
    for (int off = 1; off < BNODES; off <<= 1) {
        int a = (tid < BNODES && tid >= off) ? lrp[tid - off] : 0;
        __syncthreads();
        if (tid < BNODES) lrp[tid] += a;
        __syncthreads();
    }
    // lrp now inclusive; convert to exclusive on write
    if (tid < BNODES) {
        int ex = lrp[tid] - lhist[tid];
        lrp[tid] = ex;
        int node = nb0 + tid;
        if (node < N) {
            rowptr[node] = base + ex;
            dinv[node] = rsqrtf((float)lhist[tid] + 1.0f);
        }
    }
    __syncthreads();
    // place into LDS stage
    int cnt_total = lrp[BNODES - 1] + lhist[BNODES - 1];
    for (int t = tid; t < SLICES * SCAP; t += 256) {
        int s = t >> SCAPSH, p = t & (SCAP - 1);
        if (p < lcnt[s]) {
            unsigned v = bk[t];
            int lc = v >> 20;
            int q = atomicAdd(&lcur[lc], 1);
            stage[lrp[lc] + q] = (int)(v & 0xFFFFFu);
        }
    }
    __syncthreads();
    // coalesced copy out
    for (int t = tid; t < cnt_total; t += 256) csr_src[base + t] = stage[t];
}

// ---- lin1: h0 = relu(x@w1+b1) raw bf16; hs0 = h0*dinv bf16 ----
constexpr int NB = 16;
__global__ __launch_bounds__(256) void k_lin1(const float* __restrict__ x,
                                              const float* __restrict__ w1,
                                              const float* __restrict__ b1,
                                              const float* __restrict__ dinv,
                                              unsigned short* __restrict__ h0,
                                              unsigned short* __restrict__ hs0, int N) {
    __shared__ float xs[NB][IN_F];
    int nb0 = blockIdx.x * NB;
    for (int t = threadIdx.x; t < NB * (IN_F / 4); t += 256) {
        int n = t >> 5, k4 = t & 31;
        int gn = nb0 + n;
        float4 v = make_float4(0.f, 0.f, 0.f, 0.f);
        if (gn < N) v = ((const float4*)x)[(long long)gn * (IN_F / 4) + k4];
        *(float4*)&xs[n][k4 * 4] = v;
    }
    __syncthreads();
    int wv = threadIdx.x >> 6;
    int c  = threadIdx.x & 63;
    int n0 = wv * 4;
    float bias = b1[c];
    float a0 = bias, a1 = bias, a2 = bias, a3 = bias;
    #pragma unroll 4
    for (int k = 0; k < IN_F; k += 4) {
        float w_0 = w1[(k + 0) * HID + c];
        float w_1 = w1[(k + 1) * HID + c];
        float w_2 = w1[(k + 2) * HID + c];
        float w_3 = w1[(k + 3) * HID + c];
        float4 x0 = *(float4*)&xs[n0 + 0][k];
        float4 x1 = *(float4*)&xs[n0 + 1][k];
        float4 x2 = *(float4*)&xs[n0 + 2][k];
        float4 x3 = *(float4*)&xs[n0 + 3][k];
        a0 = fmaf(x0.x, w_0, a0); a0 = fmaf(x0.y, w_1, a0);
        a0 = fmaf(x0.z, w_2, a0); a0 = fmaf(x0.w, w_3, a0);
        a1 = fmaf(x1.x, w_0, a1); a1 = fmaf(x1.y, w_1, a1);
        a1 = fmaf(x1.z, w_2, a1); a1 = fmaf(x1.w, w_3, a1);
        a2 = fmaf(x2.x, w_0, a2); a2 = fmaf(x2.y, w_1, a2);
        a2 = fmaf(x2.z, w_2, a2); a2 = fmaf(x2.w, w_3, a2);
        a3 = fmaf(x3.x, w_0, a3); a3 = fmaf(x3.y, w_1, a3);
        a3 = fmaf(x3.z, w_2, a3); a3 = fmaf(x3.w, w_3, a3);
    }
    float acc[4] = {a0, a1, a2, a3};
    #pragma unroll
    for (int n = 0; n < 4; ++n) {
        int gn = nb0 + n0 + n;
        if (gn < N) {
            float r = fmaxf(acc[n], 0.f);
            h0 [(long long)gn * HID + c] = f2bf(r);
            hs0[(long long)gn * HID + c] = f2bf(r * dinv[gn]);
        }
    }
}

// ---- fused GCN2 layer (unchanged) ----
__global__ __launch_bounds__(256) void k_layer(const int* __restrict__ rowptr,
                                               const int* __restrict__ csr_src,
                                               const float* __restrict__ dinv,
                                               const unsigned short* __restrict__ hs_in,
                                               const unsigned short* __restrict__ h0,
                                               const float* __restrict__ W,
                                               float beta, int scale_out,
                                               unsigned short* __restrict__ h_out, int N) {
    __shared__ float ss[4][HID];
    const uint4* hin4 = (const uint4*)hs_in;
    const uint4* h04  = (const uint4*)h0;
    int wv = threadIdx.x >> 6;
    int l  = threadIdx.x & 63;
    int q  = l >> 3;
    int m  = l & 7;
    int node = blockIdx.x * 4 + wv;

    if (node < N) {
        float a[8] = {0.f, 0.f, 0.f, 0.f, 0.f, 0.f, 0.f, 0.f};
        int e0 = rowptr[node], e1 = rowptr[node + 1];
        int e = e0;
        for (; e + 16 <= e1; e += 16) {
            int r0 = csr_src[e + q];
            int r1 = csr_src[e + 8 + q];
            uint4 v0 = hin4[(long long)r0 * 8 + m];
            uint4 v1 = hin4[(long long)r1 * 8 + m];
            acc8(a, v0);
            acc8(a, v1);
        }
        if (e < e1) {
            int ee0 = e + q, ee1 = e + 8 + q;
            if (ee0 < e1) {
                int r = csr_src[ee0];
                uint4 v = hin4[(long long)r * 8 + m];
                acc8(a, v);
            }
            if (ee1 < e1) {
                int r = csr_src[ee1];
                uint4 v = hin4[(long long)r * 8 + m];
                acc8(a, v);
            }
        }
        #pragma unroll
        for (int off = 8; off <= 32; off <<= 1) {
            #pragma unroll
            for (int j = 0; j < 8; ++j) a[j] += __shfl_xor(a[j], off, 64);
        }
        if (q == 0) {
            float di = dinv[node];
            uint4 hv = hin4[(long long)node * 8 + m];
            uint4 rv = h04 [(long long)node * 8 + m];
            float hs[8] = {lo16(hv.x), hi16(hv.x), lo16(hv.y), hi16(hv.y),
                           lo16(hv.z), hi16(hv.z), lo16(hv.w), hi16(hv.w)};
            float r0[8] = {lo16(rv.x), hi16(rv.x), lo16(rv.y), hi16(rv.y),
                           lo16(rv.z), hi16(rv.z), lo16(rv.w), hi16(rv.w)};
            float s[8];
            #pragma unroll
            for (int j = 0; j < 8; ++j)
                s[j] = fmaf(0.9f * di, a[j] + hs[j], 0.1f * r0[j]);
            *(float4*)&ss[wv][8 * m]     = make_float4(s[0], s[1], s[2], s[3]);
            *(float4*)&ss[wv][8 * m + 4] = make_float4(s[4], s[5], s[6], s[7]);
        }
    }
    __syncthreads();
    if (node >= N) return;
    int c = l;
    float s = ss[wv][c];
    float mm = 0.f;
    const float4* ssv = (const float4*)&ss[wv][0];
    #pragma unroll
    for (int k4 = 0; k4 < 16; ++k4) {
        float4 sv = ssv[k4];
        mm = fmaf(sv.x, W[(4 * k4 + 0) * HID + c], mm);
        mm = fmaf(sv.y, W[(4 * k4 + 1) * HID + c], mm);
        mm = fmaf(sv.z, W[(4 * k4 + 2) * HID + c], mm);
        mm = fmaf(sv.w, W[(4 * k4 + 3) * HID + c], mm);
    }
    float v = fmaxf(s + beta * (mm - s), 0.f);
    if (scale_out) v *= dinv[node];
    h_out[(long long)node * HID + c] = f2bf(v);
}

// ---- pooling: batch SORTED -> register-accumulate, flush on boundary ----
constexpr int POOL_CHUNK = 256;
__global__ __launch_bounds__(256) void k_pool(const unsigned short* __restrict__ h,
                                              const void* batch, const int* f64,
                                              float* psum, float* pcnt, int N) {
    int c = threadIdx.x & 63;
    int g = threadIdx.x >> 6;
    int n0 = blockIdx.x * POOL_CHUNK;
    int nend = min(n0 + POOL_CHUNK, N);
    int is64 = *f64;
    float sum = 0.f;
    int cnt = 0, curb = -1;
    for (int n = n0 + g; n < nend; n += 4) {
        int b = ld_idx(batch, n, is64);
        if (b != curb) {
            if (curb >= 0) {
                atomicAdd(&psum[(long long)curb * HID + c], sum);
                if (c == 0) atomicAdd(&pcnt[curb], (float)cnt);
            }
            curb = b; sum = 0.f; cnt = 0;
        }
        sum += bf2f(h[(long long)n * HID + c]);
        cnt++;
    }
    if (curb >= 0) {
        atomicAdd(&psum[(long long)curb * HID + c], sum);
        if (c == 0) atomicAdd(&pcnt[curb], (float)cnt);
    }
}

// ---- out[g] = (psum[g]/max(cnt,1)) @ w2 + b2 ----
__global__ void k_out(const float* __restrict__ psum, const float* __restrict__ pcnt,
                      const float* __restrict__ w2, const float* __restrict__ b2,
                      float* __restrict__ out) {
    int g = blockIdx.x;
    int tid = threadIdx.x;   // 64
    __shared__ float pr[HID];
    float cnt = fmaxf(pcnt[g], 1.0f);
    pr[tid] = psum[(long long)g * HID + tid] / cnt;
    __syncthreads();
    if (tid < OUT_F) {
        float acc = b2[tid];
        #pragma unroll
        for (int k = 0; k < HID; ++k)
            acc = fmaf(pr[k], w2[k * OUT_F + tid], acc);
        out[g * OUT_F + tid] = acc;
    }
}

static inline size_t align256(size_t x) { return (x + 255) & ~(size_t)255; }

extern "C" void kernel_launch(void* const* d_in, const int* in_sizes, int n_in,
                              void* d_out, int out_size, void* d_ws, size_t ws_size,
                              hipStream_t stream) {
    const float* x     = (const float*)d_in[0];
    const void*  eidx  = d_in[1];
    const void*  batch = d_in[2];
    const float* w1    = (const float*)d_in[3];
    const float* b1    = (const float*)d_in[4];
    const float* convw = (const float*)d_in[5];
    const float* w2    = (const float*)d_in[6];
    const float* b2    = (const float*)d_in[7];
    float* out = (float*)d_out;

    int N = in_sizes[0] / IN_F;
    int E = in_sizes[1] / 2;
    int nbuk = (N + BNODES - 1) >> BSH;

    char* ws = (char*)d_ws;
    float* dinv    = (float*)ws;                ws += align256((size_t)N * 4);
    unsigned short* h0  = (unsigned short*)ws;  ws += align256((size_t)N * HID * 2);
    unsigned short* hs0 = (unsigned short*)ws;  ws += align256((size_t)N * HID * 2);
    unsigned short* hb  = (unsigned short*)ws;  ws += align256((size_t)N * HID * 2);
    float* psum    = (float*)ws;                ws += align256((size_t)NG * HID * 4);
    float* pcnt    = (float*)ws;                ws += align256((size_t)NG * 4);
    int*   rowptr  = (int*)ws;                  ws += align256((size_t)(N + 1) * 4);
    int*   csr_src = (int*)ws;                  ws += align256((size_t)E * 4);
    int*   gcur    = (int*)ws;                  ws += align256((size_t)nbuk * SLICES * 4);
    int*   gofs    = (int*)ws;                  ws += align256((size_t)(nbuk + 1) * 4);
    unsigned* bucketed = (unsigned*)ws;         ws += align256((size_t)nbuk * SLICES * SCAP * 4);
    int*   flag    = (int*)ws;

    // 1. dtype detect
    k_detect<<<1, 256, 0, stream>>>((const unsigned int*)eidx, 4096, flag);

    // 2. sliced-bucket CSR build (+ rowptr, dinv)
    hipMemsetAsync(gcur, 0, (size_t)nbuk * SLICES * 4, stream);
    k_bucket<<<(E + 255) / 256, 256, 0, stream>>>(eidx, flag, E, gcur, bucketed);
    k_bscan<<<1, 512, 0, stream>>>(gcur, gofs, nbuk, rowptr, N);
    k_bfill<<<nbuk, 256, 0, stream>>>(gcur, gofs, bucketed, rowptr, dinv, csr_src, N);

    // 3. lin1 -> h0 (raw) + hs0 (scaled)
    k_lin1<<<(N + NB - 1) / NB, 256, 0, stream>>>(x, w1, b1, dinv, h0, hs0, N);

    // 4. three fused GCN2 layers: hs0 -> hb -> hs0 -> hb(raw)
    int nlb = (N + 3) / 4;
    float beta0 = logf(0.5f / 1.0f + 1.0f);
    float beta1 = logf(0.5f / 2.0f + 1.0f);
    float beta2 = logf(0.5f / 3.0f + 1.0f);
    k_layer<<<nlb, 256, 0, stream>>>(rowptr, csr_src, dinv, hs0, h0,
                                     convw + 0 * HID * HID, beta0, 1, hb, N);
    k_layer<<<nlb, 256, 0, stream>>>(rowptr, csr_src, dinv, hb, h0,
                                     convw + 1 * HID * HID, beta1, 1, hs0, N);
    k_layer<<<nlb, 256, 0, stream>>>(rowptr, csr_src, dinv, hs0, h0,
                                     convw + 2 * HID * HID, beta2, 0, hb, N);

    // 5. pooling + final linear (raw h is hb)
    hipMemsetAsync(psum, 0, ((size_t)NG * HID + NG) * 4, stream);
    k_pool<<<(N + POOL_CHUNK - 1) / POOL_CHUNK, 256, 0, stream>>>(hb, batch, flag,
                                                                  psum, pcnt, N);
    k_out<<<NG, 64, 0, stream>>>(psum, pcnt, w2, b2, out);
}

// Round 9
// 217.251 us; speedup vs baseline: 2.2410x; 1.1593x over previous
//
#include <hip/hip_runtime.h>
#include <hip/hip_fp16.h>
#include <math.h>

constexpr int IN_F = 128;
constexpr int HID  = 64;
constexpr int OUT_F = 10;
constexpr int NG   = 256;
constexpr int BSH  = 7;            // 128 nodes per bucket
constexpr int BNODES = 1 << BSH;
constexpr int SLICES = 32;
constexpr int SCAP = 128;
constexpr int SCAPSH = 7;

typedef _Float16 half8 __attribute__((ext_vector_type(8)));
typedef float f32x4 __attribute__((ext_vector_type(4)));

// ---- int32/int64 detection ----
__global__ void k_detect(const unsigned int* w, int nwords, int* flag) {
    __shared__ int nz;
    if (threadIdx.x == 0) nz = 0;
    __syncthreads();
    int seen = 0;
    for (int i = 1 + 2 * (int)threadIdx.x; i < nwords; i += 2 * (int)blockDim.x)
        if (w[i] != 0u) seen = 1;
    if (seen) atomicOr(&nz, 1);
    __syncthreads();
    if (threadIdx.x == 0) *flag = (nz == 0) ? 1 : 0;
}

__device__ __forceinline__ int ld_idx(const void* p, long long i, int is64) {
    return is64 ? (int)((const long long*)p)[i] : ((const int*)p)[i];
}

// ---- pass 1: bucket edges by col>>BSH into 32-sliced regions ----
__global__ void k_bucket(const void* eidx, const int* f64, int E,
                         int* gcur, unsigned* bucketed) {
    int e = blockIdx.x * blockDim.x + threadIdx.x;
    if (e >= E) return;
    int is64 = *f64;
    int r = ld_idx(eidx, e, is64);
    int c = ld_idx(eidx, (long long)E + e, is64);
    int b = c >> BSH;
    int s = (e >> 8) & (SLICES - 1);
    int reg = b * SLICES + s;
    int pos = atomicAdd(&gcur[reg], 1);
    if (pos < SCAP)
        bucketed[((long long)reg << SCAPSH) + pos] =
            (unsigned)r | ((unsigned)(c & (BNODES - 1)) << 20);
}

// ---- scan per-bucket totals -> bucket edge offsets ----
__global__ __launch_bounds__(512) void k_bscan(const int* __restrict__ gcur,
                                               int* __restrict__ gofs, int nbuk,
                                               int* rowptr, int N) {
    __shared__ int tot[512];
    int tid = threadIdx.x;
    int chunk = (nbuk + 511) / 512;
    int st = tid * chunk, en = min(st + chunk, nbuk);
    int s = 0;
    for (int i = st; i < en; ++i) {
        int t = 0;
        for (int k = 0; k < SLICES; ++k) t += min(gcur[i * SLICES + k], SCAP);
        s += t;
    }
    tot[tid] = s;
    __syncthreads();
    for (int off = 1; off < 512; off <<= 1) {
        int a = (tid >= off) ? tot[tid - off] : 0;
        __syncthreads();
        tot[tid] += a;
        __syncthreads();
    }
    int run = tot[tid] - s;
    for (int i = st; i < en; ++i) {
        gofs[i] = run;
        int t = 0;
        for (int k = 0; k < SLICES; ++k) t += min(gcur[i * SLICES + k], SCAP);
        run += t;
    }
    if (tid == 511) rowptr[N] = tot[511];
}

// ---- pass 2: per-bucket local counting sort -> rowptr, dinv, csr_src ----
__global__ __launch_bounds__(256) void k_bfill(const int* __restrict__ gcur,
                                               const int* __restrict__ gofs,
                                               const unsigned* __restrict__ bucketed,
                                               int* __restrict__ rowptr,
                                               float* __restrict__ dinv,
                                               int* __restrict__ csr_src, int N) {
    __shared__ int lcnt[SLICES];
    __shared__ int lhist[BNODES], lrp[BNODES], lcur[BNODES];
    __shared__ int stage[SLICES * SCAP];
    int b = blockIdx.x;
    int base = gofs[b];
    int nb0 = b << BSH;
    int tid = threadIdx.x;
    const unsigned* bk = bucketed + ((long long)(b * SLICES) << SCAPSH);
    if (tid < SLICES) lcnt[tid] = min(gcur[b * SLICES + tid], SCAP);
    if (tid < BNODES) { lhist[tid] = 0; lcur[tid] = 0; }
    __syncthreads();
    for (int t = tid; t < SLICES * SCAP; t += 256) {
        int s = t >> SCAPSH, p = t & (SCAP - 1);
        if (p < lcnt[s]) atomicAdd(&lhist[bk[t] >> 20], 1);
    }
    __syncthreads();
    if (tid < BNODES) lrp[tid] = lhist[tid];
    __syncthreads();
    for (int off = 1; off < BNODES; off <<= 1) {
        int a = (tid < BNODES && tid >= off) ? lrp[tid - off] : 0;
        __syncthreads();
        if (tid < BNODES) lrp[tid] += a;
        __syncthreads();
    }
    if (tid < BNODES) {
        int ex = lrp[tid] - lhist[tid];
        lrp[tid] = ex;
        int node = nb0 + tid;
        if (node < N) {
            rowptr[node] = base + ex;
            dinv[node] = rsqrtf((float)lhist[tid] + 1.0f);
        }
    }
    __syncthreads();
    int cnt_total = lrp[BNODES - 1] + lhist[BNODES - 1];
    for (int t = tid; t < SLICES * SCAP; t += 256) {
        int s = t >> SCAPSH, p = t & (SCAP - 1);
        if (p < lcnt[s]) {
            unsigned v = bk[t];
            int lc = v >> 20;
            int q = atomicAdd(&lcur[lc], 1);
            stage[lrp[lc] + q] = (int)(v & 0xFFFFFu);
        }
    }
    __syncthreads();
    for (int t = tid; t < cnt_total; t += 256) csr_src[base + t] = stage[t];
}

// ---- lin1: h0 = relu(x@w1+b1) raw f16; hs0 = h0*dinv f16 ----
constexpr int NBK = 16;
__global__ __launch_bounds__(256) void k_lin1(const float* __restrict__ x,
                                              const float* __restrict__ w1,
                                              const float* __restrict__ b1,
                                              const float* __restrict__ dinv,
                                              unsigned short* __restrict__ h0,
                                              unsigned short* __restrict__ hs0, int N) {
    __shared__ float xs[NBK][IN_F];
    int nb0 = blockIdx.x * NBK;
    for (int t = threadIdx.x; t < NBK * (IN_F / 4); t += 256) {
        int n = t >> 5, k4 = t & 31;
        int gn = nb0 + n;
        float4 v = make_float4(0.f, 0.f, 0.f, 0.f);
        if (gn < N) v = ((const float4*)x)[(long long)gn * (IN_F / 4) + k4];
        *(float4*)&xs[n][k4 * 4] = v;
    }
    __syncthreads();
    int wv = threadIdx.x >> 6;
    int c  = threadIdx.x & 63;
    int n0 = wv * 4;
    float bias = b1[c];
    float a0 = bias, a1 = bias, a2 = bias, a3 = bias;
    #pragma unroll 4
    for (int k = 0; k < IN_F; k += 4) {
        float w_0 = w1[(k + 0) * HID + c];
        float w_1 = w1[(k + 1) * HID + c];
        float w_2 = w1[(k + 2) * HID + c];
        float w_3 = w1[(k + 3) * HID + c];
        float4 x0 = *(float4*)&xs[n0 + 0][k];
        float4 x1 = *(float4*)&xs[n0 + 1][k];
        float4 x2 = *(float4*)&xs[n0 + 2][k];
        float4 x3 = *(float4*)&xs[n0 + 3][k];
        a0 = fmaf(x0.x, w_0, a0); a0 = fmaf(x0.y, w_1, a0);
        a0 = fmaf(x0.z, w_2, a0); a0 = fmaf(x0.w, w_3, a0);
        a1 = fmaf(x1.x, w_0, a1); a1 = fmaf(x1.y, w_1, a1);
        a1 = fmaf(x1.z, w_2, a1); a1 = fmaf(x1.w, w_3, a1);
        a2 = fmaf(x2.x, w_0, a2); a2 = fmaf(x2.y, w_1, a2);
        a2 = fmaf(x2.z, w_2, a2); a2 = fmaf(x2.w, w_3, a2);
        a3 = fmaf(x3.x, w_0, a3); a3 = fmaf(x3.y, w_1, a3);
        a3 = fmaf(x3.z, w_2, a3); a3 = fmaf(x3.w, w_3, a3);
    }
    float acc[4] = {a0, a1, a2, a3};
    #pragma unroll
    for (int n = 0; n < 4; ++n) {
        int gn = nb0 + n0 + n;
        if (gn < N) {
            float r = fmaxf(acc[n], 0.f);
            __half hr = __float2half(r);
            __half hs = __float2half(r * dinv[gn]);
            h0 [(long long)gn * HID + c] = *(unsigned short*)&hr;
            hs0[(long long)gn * HID + c] = *(unsigned short*)&hs;
        }
    }
}

// ---- fused GCN2 layer v4: f16 pk-add gather + MFMA s@W epilogue ----
// block = 256 thr (4 waves) = 16 nodes. s_lds/wt_lds XOR-swizzled (16B blocks).
__global__ __launch_bounds__(256) void k_layer(const int* __restrict__ rowptr,
                                               const int* __restrict__ csr_src,
                                               const float* __restrict__ dinv,
                                               const unsigned short* __restrict__ hs_in,
                                               const unsigned short* __restrict__ h0,
                                               const float* __restrict__ W,
                                               float beta, int scale_out,
                                               unsigned short* __restrict__ h_out, int N) {
    __shared__ unsigned short s_lds[16][HID];    // f16 s, swizzled
    __shared__ unsigned short wt_lds[HID][HID];  // f16 W^T [n][k], swizzled
    int tid = threadIdx.x;
    int l = tid & 63, wv = tid >> 6;
    int nb = blockIdx.x * 16;

    // ---- stage W^T into LDS as f16 (thread: n = tid>>2, k0 = (tid&3)*16) ----
    {
        int n = tid >> 2, k0 = (tid & 3) * 16;
        __attribute__((aligned(16))) _Float16 tmp[16];
        #pragma unroll
        for (int i = 0; i < 16; ++i)
            tmp[i] = (_Float16)W[(k0 + i) * HID + n];
        #pragma unroll
        for (int b2 = 0; b2 < 2; ++b2) {
            int kb = (k0 >> 3) + b2;
            int slot = kb ^ (n & 7);
            *(uint4*)&wt_lds[n][slot * 8] = *(uint4*)&tmp[b2 * 8];
        }
    }

    // ---- gather: wave wv handles nodes nb+4*wv .. +3 (serial) ----
    const uint4* hin4 = (const uint4*)hs_in;
    const uint4* h04  = (const uint4*)h0;
    int q = l >> 3, m = l & 7;
    for (int j = 0; j < 4; ++j) {
        int row = wv * 4 + j;
        int node = nb + row;
        if (node < N) {
            __half2 a[4] = {__half2(0.f, 0.f), __half2(0.f, 0.f),
                            __half2(0.f, 0.f), __half2(0.f, 0.f)};
            int e0 = rowptr[node], e1 = rowptr[node + 1];
            int e = e0;
            for (; e + 16 <= e1; e += 16) {
                int r0 = csr_src[e + q];
                int r1 = csr_src[e + 8 + q];
                uint4 v0 = hin4[(long long)r0 * 8 + m];
                uint4 v1 = hin4[(long long)r1 * 8 + m];
                const __half2* p0 = (const __half2*)&v0;
                const __half2* p1 = (const __half2*)&v1;
                #pragma unroll
                for (int jj = 0; jj < 4; ++jj) a[jj] = __hadd2(a[jj], p0[jj]);
                #pragma unroll
                for (int jj = 0; jj < 4; ++jj) a[jj] = __hadd2(a[jj], p1[jj]);
            }
            if (e < e1) {
                int ee0 = e + q, ee1 = e + 8 + q;
                if (ee0 < e1) {
                    uint4 v = hin4[(long long)csr_src[ee0] * 8 + m];
                    const __half2* p = (const __half2*)&v;
                    #pragma unroll
                    for (int jj = 0; jj < 4; ++jj) a[jj] = __hadd2(a[jj], p[jj]);
                }
                if (ee1 < e1) {
                    uint4 v = hin4[(long long)csr_src[ee1] * 8 + m];
                    const __half2* p = (const __half2*)&v;
                    #pragma unroll
                    for (int jj = 0; jj < 4; ++jj) a[jj] = __hadd2(a[jj], p[jj]);
                }
            }
            // butterfly fold: every lane ends with full channel sums for its octet m
            #pragma unroll
            for (int off = 8; off <= 32; off <<= 1) {
                #pragma unroll
                for (int jj = 0; jj < 4; ++jj) {
                    unsigned t = __shfl_xor(*(unsigned*)&a[jj], off, 64);
                    a[jj] = __hadd2(a[jj], *(__half2*)&t);
                }
            }
            if (l < 8) {   // m == l: finalize s for channels 8m..8m+7
                float di = dinv[node];
                uint4 hv = hin4[(long long)node * 8 + m];   // self (pre-scaled)
                uint4 rv = h04 [(long long)node * 8 + m];   // residual (raw)
                const __half2* hp = (const __half2*)&hv;
                const __half2* rp = (const __half2*)&rv;
                __attribute__((aligned(16))) unsigned short out8[8];
                #pragma unroll
                for (int jj = 0; jj < 4; ++jj) {
                    __half2 t = __hadd2(a[jj], hp[jj]);
                    float slo = fmaf(0.9f * di, __low2float(t),  0.1f * __low2float(rp[jj]));
                    float shi = fmaf(0.9f * di, __high2float(t), 0.1f * __high2float(rp[jj]));
                    *(__half2*)&out8[jj * 2] = __floats2half2_rn(slo, shi);
                }
                int slot = m ^ (row & 7);
                *(uint4*)&s_lds[row][slot * 8] = *(uint4*)out8;
            }
        } else if (l < 8) {
            int slot = m ^ (row & 7);
            uint4 z = make_uint4(0, 0, 0, 0);
            *(uint4*)&s_lds[row][slot * 8] = z;
        }
    }
    __syncthreads();

    // ---- MFMA: wave wv computes output cols 16*wv .. 16*wv+15 ----
    int i16 = l & 15, kc = l >> 4;        // A row / B col = i16; k-chunk = kc
    f32x4 acc = {0.f, 0.f, 0.f, 0.f};
    #pragma unroll
    for (int ks = 0; ks < 2; ++ks) {
        int cb = ks * 4 + kc;                       // 8-channel block index
        int sa = cb ^ (i16 & 7);
        half8 av = *(half8*)&s_lds[i16][sa * 8];
        int n = wv * 16 + i16;
        int sb = cb ^ (n & 7);
        half8 bv = *(half8*)&wt_lds[n][sb * 8];
        acc = __builtin_amdgcn_mfma_f32_16x16x32_f16(av, bv, acc, 0, 0, 0);
    }
    // epilogue: D col = i16 (+16*wv), row = kc*4 + r
    #pragma unroll
    for (int r = 0; r < 4; ++r) {
        int row = kc * 4 + r;
        int node = nb + row;
        if (node < N) {
            int colg = wv * 16 + i16;
            int slot = (colg >> 3) ^ (row & 7);
            __half sh = *(__half*)&s_lds[row][slot * 8 + (colg & 7)];
            float sv = __half2float(sh);
            float v = fmaxf(sv + beta * (acc[r] - sv), 0.f);
            if (scale_out) v *= dinv[node];
            __half hv2 = __float2half(v);
            h_out[(long long)node * HID + colg] = *(unsigned short*)&hv2;
        }
    }
}

// ---- pooling: batch SORTED -> register-accumulate, flush on boundary ----
constexpr int POOL_CHUNK = 256;
__global__ __launch_bounds__(256) void k_pool(const unsigned short* __restrict__ h,
                                              const void* batch, const int* f64,
                                              float* psum, float* pcnt, int N) {
    int c = threadIdx.x & 63;
    int g = threadIdx.x >> 6;
    int n0 = blockIdx.x * POOL_CHUNK;
    int nend = min(n0 + POOL_CHUNK, N);
    int is64 = *f64;
    float sum = 0.f;
    int cnt = 0, curb = -1;
    for (int n = n0 + g; n < nend; n += 4) {
        int b = ld_idx(batch, n, is64);
        if (b != curb) {
            if (curb >= 0) {
                atomicAdd(&psum[(long long)curb * HID + c], sum);
                if (c == 0) atomicAdd(&pcnt[curb], (float)cnt);
            }
            curb = b; sum = 0.f; cnt = 0;
        }
        __half hv = *(__half*)&h[(long long)n * HID + c];
        sum += __half2float(hv);
        cnt++;
    }
    if (curb >= 0) {
        atomicAdd(&psum[(long long)curb * HID + c], sum);
        if (c == 0) atomicAdd(&pcnt[curb], (float)cnt);
    }
}

// ---- out[g] = (psum[g]/max(cnt,1)) @ w2 + b2 ----
__global__ void k_out(const float* __restrict__ psum, const float* __restrict__ pcnt,
                      const float* __restrict__ w2, const float* __restrict__ b2,
                      float* __restrict__ out) {
    int g = blockIdx.x;
    int tid = threadIdx.x;   // 64
    __shared__ float pr[HID];
    float cnt = fmaxf(pcnt[g], 1.0f);
    pr[tid] = psum[(long long)g * HID + tid] / cnt;
    __syncthreads();
    if (tid < OUT_F) {
        float acc = b2[tid];
        #pragma unroll
        for (int k = 0; k < HID; ++k)
            acc = fmaf(pr[k], w2[k * OUT_F + tid], acc);
        out[g * OUT_F + tid] = acc;
    }
}

static inline size_t align256(size_t x) { return (x + 255) & ~(size_t)255; }

extern "C" void kernel_launch(void* const* d_in, const int* in_sizes, int n_in,
                              void* d_out, int out_size, void* d_ws, size_t ws_size,
                              hipStream_t stream) {
    const float* x     = (const float*)d_in[0];
    const void*  eidx  = d_in[1];
    const void*  batch = d_in[2];
    const float* w1    = (const float*)d_in[3];
    const float* b1    = (const float*)d_in[4];
    const float* convw = (const float*)d_in[5];
    const float* w2    = (const float*)d_in[6];
    const float* b2    = (const float*)d_in[7];
    float* out = (float*)d_out;

    int N = in_sizes[0] / IN_F;
    int E = in_sizes[1] / 2;
    int nbuk = (N + BNODES - 1) >> BSH;

    char* ws = (char*)d_ws;
    float* dinv    = (float*)ws;                ws += align256((size_t)N * 4);
    unsigned short* h0  = (unsigned short*)ws;  ws += align256((size_t)N * HID * 2);
    unsigned short* hs0 = (unsigned short*)ws;  ws += align256((size_t)N * HID * 2);
    unsigned short* hb  = (unsigned short*)ws;  ws += align256((size_t)N * HID * 2);
    float* psum    = (float*)ws;                ws += align256((size_t)NG * HID * 4);
    float* pcnt    = (float*)ws;                ws += align256((size_t)NG * 4);
    int*   rowptr  = (int*)ws;                  ws += align256((size_t)(N + 1) * 4);
    int*   csr_src = (int*)ws;                  ws += align256((size_t)E * 4);
    int*   gcur    = (int*)ws;                  ws += align256((size_t)nbuk * SLICES * 4);
    int*   gofs    = (int*)ws;                  ws += align256((size_t)(nbuk + 1) * 4);
    unsigned* bucketed = (unsigned*)ws;         ws += align256((size_t)nbuk * SLICES * SCAP * 4);
    int*   flag    = (int*)ws;

    // 1. dtype detect
    k_detect<<<1, 256, 0, stream>>>((const unsigned int*)eidx, 4096, flag);

    // 2. sliced-bucket CSR build (+ rowptr, dinv)
    hipMemsetAsync(gcur, 0, (size_t)nbuk * SLICES * 4, stream);
    k_bucket<<<(E + 255) / 256, 256, 0, stream>>>(eidx, flag, E, gcur, bucketed);
    k_bscan<<<1, 512, 0, stream>>>(gcur, gofs, nbuk, rowptr, N);
    k_bfill<<<nbuk, 256, 0, stream>>>(gcur, gofs, bucketed, rowptr, dinv, csr_src, N);

    // 3. lin1 -> h0 (raw f16) + hs0 (scaled f16)
    k_lin1<<<(N + NBK - 1) / NBK, 256, 0, stream>>>(x, w1, b1, dinv, h0, hs0, N);

    // 4. three fused GCN2 layers: hs0 -> hb -> hs0 -> hb(raw)
    int nlb = (N + 15) / 16;
    float beta0 = logf(0.5f / 1.0f + 1.0f);
    float beta1 = logf(0.5f / 2.0f + 1.0f);
    float beta2 = logf(0.5f / 3.0f + 1.0f);
    k_layer<<<nlb, 256, 0, stream>>>(rowptr, csr_src, dinv, hs0, h0,
                                     convw + 0 * HID * HID, beta0, 1, hb, N);
    k_layer<<<nlb, 256, 0, stream>>>(rowptr, csr_src, dinv, hb, h0,
                                     convw + 1 * HID * HID, beta1, 1, hs0, N);
    k_layer<<<nlb, 256, 0, stream>>>(rowptr, csr_src, dinv, hs0, h0,
                                     convw + 2 * HID * HID, beta2, 0, hb, N);

    // 5. pooling + final linear (raw h is hb)
    hipMemsetAsync(psum, 0, ((size_t)NG * HID + NG) * 4, stream);
    k_pool<<<(N + POOL_CHUNK - 1) / POOL_CHUNK, 256, 0, stream>>>(hb, batch, flag,
                                                                  psum, pcnt, N);
    k_out<<<NG, 64, 0, stream>>>(psum, pcnt, w2, b2, out);
}

// Round 10
// 179.109 us; speedup vs baseline: 2.7182x; 1.2130x over previous
//
#include <hip/hip_runtime.h>
#include <hip/hip_fp16.h>
#include <math.h>

constexpr int IN_F = 128;
constexpr int HID  = 64;
constexpr int OUT_F = 10;
constexpr int NG   = 256;
constexpr int BSH  = 7;            // 128 nodes per bucket
constexpr int BNODES = 1 << BSH;
constexpr int CAP  = 3072;         // per-bucket edge capacity (mean ~2046)
constexpr int NBUK_MAX = 1024;     // supports N <= 131072
constexpr int EPB  = 8192;         // edges per bucket-sort block

typedef _Float16 half8 __attribute__((ext_vector_type(8)));
typedef float f32x4 __attribute__((ext_vector_type(4)));

// ---- int32/int64 detection ----
__global__ void k_detect(const unsigned int* w, int nwords, int* flag) {
    __shared__ int nz;
    if (threadIdx.x == 0) nz = 0;
    __syncthreads();
    int seen = 0;
    for (int i = 1 + 2 * (int)threadIdx.x; i < nwords; i += 2 * (int)blockDim.x)
        if (w[i] != 0u) seen = 1;
    if (seen) atomicOr(&nz, 1);
    __syncthreads();
    if (threadIdx.x == 0) *flag = (nz == 0) ? 1 : 0;
}

__device__ __forceinline__ int ld_idx(const void* p, long long i, int is64) {
    return is64 ? (int)((const long long*)p)[i] : ((const int*)p)[i];
}

// ---- pass 1: block-level counting sort into contiguous per-bucket regions ----
// 1024 thr, 8192 edges/block. One global atomic per (block,bucket).
__global__ __launch_bounds__(1024) void k_bucket2(const void* eidx, const int* f64,
                                                  int E, int nbuk,
                                                  int* gcur, unsigned* bucketed) {
    __shared__ int lhist[NBUK_MAX];          // counts, then global bases
    __shared__ int lofs[NBUK_MAX];           // inclusive local scan
    __shared__ int lcur[NBUK_MAX];
    __shared__ unsigned stage[EPB];
    __shared__ unsigned short sbid[EPB];
    int tid = threadIdx.x;
    long long base = (long long)blockIdx.x * EPB;
    int nval = (int)min((long long)EPB, (long long)E - base);
    int is64 = *f64;
    lhist[tid] = 0; lcur[tid] = 0;
    __syncthreads();
    unsigned pv[8]; int bv[8];
    #pragma unroll
    for (int j = 0; j < 8; ++j) {
        long long e = base + j * 1024 + tid;
        if (e < E) {
            int r = ld_idx(eidx, e, is64);
            int c = ld_idx(eidx, (long long)E + e, is64);
            int b = c >> BSH;
            pv[j] = (unsigned)r | ((unsigned)(c & (BNODES - 1)) << 20);
            bv[j] = b;
            atomicAdd(&lhist[b], 1);
        } else bv[j] = -1;
    }
    __syncthreads();
    lofs[tid] = lhist[tid];
    __syncthreads();
    for (int off = 1; off < NBUK_MAX; off <<= 1) {
        int v = (tid >= off) ? lofs[tid - off] : 0;
        __syncthreads();
        lofs[tid] += v;
        __syncthreads();
    }
    int cnt = lhist[tid];
    if (tid < nbuk && cnt > 0)
        lhist[tid] = atomicAdd(&gcur[tid], cnt);   // overwrite count with global base
    // place into LDS stage (sorted by bucket)
    #pragma unroll
    for (int j = 0; j < 8; ++j) {
        if (bv[j] >= 0) {
            int b = bv[j];
            int ex = (b > 0) ? lofs[b - 1] : 0;
            int p = ex + atomicAdd(&lcur[b], 1);
            stage[p] = pv[j];
            sbid[p] = (unsigned short)b;
        }
    }
    __syncthreads();
    // contiguous copy-out per bucket-group
    for (int p = tid; p < nval; p += 1024) {
        int b = sbid[p];
        int ex = (b > 0) ? lofs[b - 1] : 0;
        int dst = lhist[b] + (p - ex);
        if (dst < CAP)
            bucketed[(long long)b * CAP + dst] = stage[p];
    }
}

// ---- fallback for nbuk > NBUK_MAX: per-edge append (correct, slower) ----
__global__ void k_bucket_fb(const void* eidx, const int* f64, int E,
                            int* gcur, unsigned* bucketed) {
    int e = blockIdx.x * blockDim.x + threadIdx.x;
    if (e >= E) return;
    int is64 = *f64;
    int r = ld_idx(eidx, e, is64);
    int c = ld_idx(eidx, (long long)E + e, is64);
    int b = c >> BSH;
    int pos = atomicAdd(&gcur[b], 1);
    if (pos < CAP)
        bucketed[(long long)b * CAP + pos] =
            (unsigned)r | ((unsigned)(c & (BNODES - 1)) << 20);
}

// ---- scan per-bucket totals -> bucket edge offsets ----
__global__ __launch_bounds__(512) void k_bscan(const int* __restrict__ gcur,
                                               int* __restrict__ gofs, int nbuk,
                                               int* rowptr, int N) {
    __shared__ int tot[512];
    int tid = threadIdx.x;
    int chunk = (nbuk + 511) / 512;
    int st = tid * chunk, en = min(st + chunk, nbuk);
    int s = 0;
    for (int i = st; i < en; ++i) s += min(gcur[i], CAP);
    tot[tid] = s;
    __syncthreads();
    for (int off = 1; off < 512; off <<= 1) {
        int a = (tid >= off) ? tot[tid - off] : 0;
        __syncthreads();
        tot[tid] += a;
        __syncthreads();
    }
    int run = tot[tid] - s;
    for (int i = st; i < en; ++i) { gofs[i] = run; run += min(gcur[i], CAP); }
    if (tid == 511) rowptr[N] = tot[511];
}

// ---- pass 2: per-bucket local counting sort -> rowptr, dinv, csr_src ----
__global__ __launch_bounds__(256) void k_bfill(const int* __restrict__ gcur,
                                               const int* __restrict__ gofs,
                                               const unsigned* __restrict__ bucketed,
                                               int* __restrict__ rowptr,
                                               float* __restrict__ dinv,
                                               int* __restrict__ csr_src, int N) {
    __shared__ int lhist[BNODES], lrp[BNODES], lcur[BNODES];
    __shared__ int stage[CAP];
    int b = blockIdx.x;
    int cnt = min(gcur[b], CAP);
    int base = gofs[b];
    int nb0 = b << BSH;
    int tid = threadIdx.x;
    const unsigned* bk = bucketed + (long long)b * CAP;
    if (tid < BNODES) { lhist[tid] = 0; lcur[tid] = 0; }
    __syncthreads();
    for (int t = tid; t < cnt; t += 256) atomicAdd(&lhist[bk[t] >> 20], 1);
    __syncthreads();
    if (tid < BNODES) lrp[tid] = lhist[tid];
    __syncthreads();
    for (int off = 1; off < BNODES; off <<= 1) {
        int a = (tid < BNODES && tid >= off) ? lrp[tid - off] : 0;
        __syncthreads();
        if (tid < BNODES) lrp[tid] += a;
        __syncthreads();
    }
    if (tid < BNODES) {
        int ex = lrp[tid] - lhist[tid];
        lrp[tid] = ex;
        int node = nb0 + tid;
        if (node < N) {
            rowptr[node] = base + ex;
            dinv[node] = rsqrtf((float)lhist[tid] + 1.0f);
        }
    }
    __syncthreads();
    for (int t = tid; t < cnt; t += 256) {
        unsigned v = bk[t];
        int lc = v >> 20;
        int q = atomicAdd(&lcur[lc], 1);
        stage[lrp[lc] + q] = (int)(v & 0xFFFFFu);
    }
    __syncthreads();
    for (int t = tid; t < cnt; t += 256) csr_src[base + t] = stage[t];
}

// ---- lin1: h0 = relu(x@w1+b1) raw f16; hs0 = h0*dinv f16 ----
constexpr int NBK = 16;
__global__ __launch_bounds__(256) void k_lin1(const float* __restrict__ x,
                                              const float* __restrict__ w1,
                                              const float* __restrict__ b1,
                                              const float* __restrict__ dinv,
                                              unsigned short* __restrict__ h0,
                                              unsigned short* __restrict__ hs0, int N) {
    __shared__ float xs[NBK][IN_F];
    int nb0 = blockIdx.x * NBK;
    for (int t = threadIdx.x; t < NBK * (IN_F / 4); t += 256) {
        int n = t >> 5, k4 = t & 31;
        int gn = nb0 + n;
        float4 v = make_float4(0.f, 0.f, 0.f, 0.f);
        if (gn < N) v = ((const float4*)x)[(long long)gn * (IN_F / 4) + k4];
        *(float4*)&xs[n][k4 * 4] = v;
    }
    __syncthreads();
    int wv = threadIdx.x >> 6;
    int c  = threadIdx.x & 63;
    int n0 = wv * 4;
    float bias = b1[c];
    float a0 = bias, a1 = bias, a2 = bias, a3 = bias;
    #pragma unroll 4
    for (int k = 0; k < IN_F; k += 4) {
        float w_0 = w1[(k + 0) * HID + c];
        float w_1 = w1[(k + 1) * HID + c];
        float w_2 = w1[(k + 2) * HID + c];
        float w_3 = w1[(k + 3) * HID + c];
        float4 x0 = *(float4*)&xs[n0 + 0][k];
        float4 x1 = *(float4*)&xs[n0 + 1][k];
        float4 x2 = *(float4*)&xs[n0 + 2][k];
        float4 x3 = *(float4*)&xs[n0 + 3][k];
        a0 = fmaf(x0.x, w_0, a0); a0 = fmaf(x0.y, w_1, a0);
        a0 = fmaf(x0.z, w_2, a0); a0 = fmaf(x0.w, w_3, a0);
        a1 = fmaf(x1.x, w_0, a1); a1 = fmaf(x1.y, w_1, a1);
        a1 = fmaf(x1.z, w_2, a1); a1 = fmaf(x1.w, w_3, a1);
        a2 = fmaf(x2.x, w_0, a2); a2 = fmaf(x2.y, w_1, a2);
        a2 = fmaf(x2.z, w_2, a2); a2 = fmaf(x2.w, w_3, a2);
        a3 = fmaf(x3.x, w_0, a3); a3 = fmaf(x3.y, w_1, a3);
        a3 = fmaf(x3.z, w_2, a3); a3 = fmaf(x3.w, w_3, a3);
    }
    float acc[4] = {a0, a1, a2, a3};
    #pragma unroll
    for (int n = 0; n < 4; ++n) {
        int gn = nb0 + n0 + n;
        if (gn < N) {
            float r = fmaxf(acc[n], 0.f);
            __half hr = __float2half(r);
            __half hs = __float2half(r * dinv[gn]);
            h0 [(long long)gn * HID + c] = *(unsigned short*)&hr;
            hs0[(long long)gn * HID + c] = *(unsigned short*)&hs;
        }
    }
}

// ---- fused GCN2 layer: f16 pk-add gather + MFMA s@W epilogue ----
__global__ __launch_bounds__(256) void k_layer(const int* __restrict__ rowptr,
                                               const int* __restrict__ csr_src,
                                               const float* __restrict__ dinv,
                                               const unsigned short* __restrict__ hs_in,
                                               const unsigned short* __restrict__ h0,
                                               const float* __restrict__ W,
                                               float beta, int scale_out,
                                               unsigned short* __restrict__ h_out, int N) {
    __shared__ unsigned short s_lds[16][HID];    // f16 s, swizzled
    __shared__ unsigned short wt_lds[HID][HID];  // f16 W^T [n][k], swizzled
    int tid = threadIdx.x;
    int l = tid & 63, wv = tid >> 6;
    int nb = blockIdx.x * 16;

    {
        int n = tid >> 2, k0 = (tid & 3) * 16;
        __attribute__((aligned(16))) _Float16 tmp[16];
        #pragma unroll
        for (int i = 0; i < 16; ++i)
            tmp[i] = (_Float16)W[(k0 + i) * HID + n];
        #pragma unroll
        for (int b2 = 0; b2 < 2; ++b2) {
            int kb = (k0 >> 3) + b2;
            int slot = kb ^ (n & 7);
            *(uint4*)&wt_lds[n][slot * 8] = *(uint4*)&tmp[b2 * 8];
        }
    }

    const uint4* hin4 = (const uint4*)hs_in;
    const uint4* h04  = (const uint4*)h0;
    int q = l >> 3, m = l & 7;
    for (int j = 0; j < 4; ++j) {
        int row = wv * 4 + j;
        int node = nb + row;
        if (node < N) {
            __half2 a[4] = {__half2(0.f, 0.f), __half2(0.f, 0.f),
                            __half2(0.f, 0.f), __half2(0.f, 0.f)};
            int e0 = rowptr[node], e1 = rowptr[node + 1];
            int e = e0;
            for (; e + 16 <= e1; e += 16) {
                int r0 = csr_src[e + q];
                int r1 = csr_src[e + 8 + q];
                uint4 v0 = hin4[(long long)r0 * 8 + m];
                uint4 v1 = hin4[(long long)r1 * 8 + m];
                const __half2* p0 = (const __half2*)&v0;
                const __half2* p1 = (const __half2*)&v1;
                #pragma unroll
                for (int jj = 0; jj < 4; ++jj) a[jj] = __hadd2(a[jj], p0[jj]);
                #pragma unroll
                for (int jj = 0; jj < 4; ++jj) a[jj] = __hadd2(a[jj], p1[jj]);
            }
            if (e < e1) {
                int ee0 = e + q, ee1 = e + 8 + q;
                if (ee0 < e1) {
                    uint4 v = hin4[(long long)csr_src[ee0] * 8 + m];
                    const __half2* p = (const __half2*)&v;
                    #pragma unroll
                    for (int jj = 0; jj < 4; ++jj) a[jj] = __hadd2(a[jj], p[jj]);
                }
                if (ee1 < e1) {
                    uint4 v = hin4[(long long)csr_src[ee1] * 8 + m];
                    const __half2* p = (const __half2*)&v;
                    #pragma unroll
                    for (int jj = 0; jj < 4; ++jj) a[jj] = __hadd2(a[jj], p[jj]);
                }
            }
            #pragma unroll
            for (int off = 8; off <= 32; off <<= 1) {
                #pragma unroll
                for (int jj = 0; jj < 4; ++jj) {
                    unsigned t = __shfl_xor(*(unsigned*)&a[jj], off, 64);
                    a[jj] = __hadd2(a[jj], *(__half2*)&t);
                }
            }
            if (l < 8) {
                float di = dinv[node];
                uint4 hv = hin4[(long long)node * 8 + m];
                uint4 rv = h04 [(long long)node * 8 + m];
                const __half2* hp = (const __half2*)&hv;
                const __half2* rp = (const __half2*)&rv;
                __attribute__((aligned(16))) unsigned short out8[8];
                #pragma unroll
                for (int jj = 0; jj < 4; ++jj) {
                    __half2 t = __hadd2(a[jj], hp[jj]);
                    float slo = fmaf(0.9f * di, __low2float(t),  0.1f * __low2float(rp[jj]));
                    float shi = fmaf(0.9f * di, __high2float(t), 0.1f * __high2float(rp[jj]));
                    *(__half2*)&out8[jj * 2] = __floats2half2_rn(slo, shi);
                }
                int slot = m ^ (row & 7);
                *(uint4*)&s_lds[row][slot * 8] = *(uint4*)out8;
            }
        } else if (l < 8) {
            int slot = m ^ (row & 7);
            uint4 z = make_uint4(0, 0, 0, 0);
            *(uint4*)&s_lds[row][slot * 8] = z;
        }
    }
    __syncthreads();

    int i16 = l & 15, kc = l >> 4;
    f32x4 acc = {0.f, 0.f, 0.f, 0.f};
    #pragma unroll
    for (int ks = 0; ks < 2; ++ks) {
        int cb = ks * 4 + kc;
        int sa = cb ^ (i16 & 7);
        half8 av = *(half8*)&s_lds[i16][sa * 8];
        int n = wv * 16 + i16;
        int sb = cb ^ (n & 7);
        half8 bv = *(half8*)&wt_lds[n][sb * 8];
        acc = __builtin_amdgcn_mfma_f32_16x16x32_f16(av, bv, acc, 0, 0, 0);
    }
    #pragma unroll
    for (int r = 0; r < 4; ++r) {
        int row = kc * 4 + r;
        int node = nb + row;
        if (node < N) {
            int colg = wv * 16 + i16;
            int slot = (colg >> 3) ^ (row & 7);
            __half sh = *(__half*)&s_lds[row][slot * 8 + (colg & 7)];
            float sv = __half2float(sh);
            float v = fmaxf(sv + beta * (acc[r] - sv), 0.f);
            if (scale_out) v *= dinv[node];
            __half hv2 = __float2half(v);
            h_out[(long long)node * HID + colg] = *(unsigned short*)&hv2;
        }
    }
}

// ---- pooling ----
constexpr int POOL_CHUNK = 256;
__global__ __launch_bounds__(256) void k_pool(const unsigned short* __restrict__ h,
                                              const void* batch, const int* f64,
                                              float* psum, float* pcnt, int N) {
    int c = threadIdx.x & 63;
    int g = threadIdx.x >> 6;
    int n0 = blockIdx.x * POOL_CHUNK;
    int nend = min(n0 + POOL_CHUNK, N);
    int is64 = *f64;
    float sum = 0.f;
    int cnt = 0, curb = -1;
    for (int n = n0 + g; n < nend; n += 4) {
        int b = ld_idx(batch, n, is64);
        if (b != curb) {
            if (curb >= 0) {
                atomicAdd(&psum[(long long)curb * HID + c], sum);
                if (c == 0) atomicAdd(&pcnt[curb], (float)cnt);
            }
            curb = b; sum = 0.f; cnt = 0;
        }
        __half hv = *(__half*)&h[(long long)n * HID + c];
        sum += __half2float(hv);
        cnt++;
    }
    if (curb >= 0) {
        atomicAdd(&psum[(long long)curb * HID + c], sum);
        if (c == 0) atomicAdd(&pcnt[curb], (float)cnt);
    }
}

// ---- out[g] = (psum[g]/max(cnt,1)) @ w2 + b2 ----
__global__ void k_out(const float* __restrict__ psum, const float* __restrict__ pcnt,
                      const float* __restrict__ w2, const float* __restrict__ b2,
                      float* __restrict__ out) {
    int g = blockIdx.x;
    int tid = threadIdx.x;
    __shared__ float pr[HID];
    float cnt = fmaxf(pcnt[g], 1.0f);
    pr[tid] = psum[(long long)g * HID + tid] / cnt;
    __syncthreads();
    if (tid < OUT_F) {
        float acc = b2[tid];
        #pragma unroll
        for (int k = 0; k < HID; ++k)
            acc = fmaf(pr[k], w2[k * OUT_F + tid], acc);
        out[g * OUT_F + tid] = acc;
    }
}

static inline size_t align256(size_t x) { return (x + 255) & ~(size_t)255; }

extern "C" void kernel_launch(void* const* d_in, const int* in_sizes, int n_in,
                              void* d_out, int out_size, void* d_ws, size_t ws_size,
                              hipStream_t stream) {
    const float* x     = (const float*)d_in[0];
    const void*  eidx  = d_in[1];
    const void*  batch = d_in[2];
    const float* w1    = (const float*)d_in[3];
    const float* b1    = (const float*)d_in[4];
    const float* convw = (const float*)d_in[5];
    const float* w2    = (const float*)d_in[6];
    const float* b2    = (const float*)d_in[7];
    float* out = (float*)d_out;

    int N = in_sizes[0] / IN_F;
    int E = in_sizes[1] / 2;
    int nbuk = (N + BNODES - 1) >> BSH;

    char* ws = (char*)d_ws;
    float* dinv    = (float*)ws;                ws += align256((size_t)N * 4);
    unsigned short* h0  = (unsigned short*)ws;  ws += align256((size_t)N * HID * 2);
    unsigned short* hs0 = (unsigned short*)ws;  ws += align256((size_t)N * HID * 2);
    unsigned short* hb  = (unsigned short*)ws;  ws += align256((size_t)N * HID * 2);
    float* psum    = (float*)ws;                ws += align256((size_t)NG * HID * 4);
    float* pcnt    = (float*)ws;                ws += align256((size_t)NG * 4);
    int*   rowptr  = (int*)ws;                  ws += align256((size_t)(N + 1) * 4);
    int*   csr_src = (int*)ws;                  ws += align256((size_t)E * 4);
    int*   gcur    = (int*)ws;                  ws += align256((size_t)nbuk * 4);
    int*   gofs    = (int*)ws;                  ws += align256((size_t)(nbuk + 1) * 4);
    unsigned* bucketed = (unsigned*)ws;         ws += align256((size_t)nbuk * CAP * 4);
    int*   flag    = (int*)ws;

    // 1. dtype detect
    k_detect<<<1, 256, 0, stream>>>((const unsigned int*)eidx, 4096, flag);

    // 2. CSR build: block counting-sort -> scan -> per-bucket sort
    hipMemsetAsync(gcur, 0, (size_t)nbuk * 4, stream);
    if (nbuk <= NBUK_MAX)
        k_bucket2<<<(E + EPB - 1) / EPB, 1024, 0, stream>>>(eidx, flag, E, nbuk,
                                                            gcur, bucketed);
    else
        k_bucket_fb<<<(E + 255) / 256, 256, 0, stream>>>(eidx, flag, E, gcur, bucketed);
    k_bscan<<<1, 512, 0, stream>>>(gcur, gofs, nbuk, rowptr, N);
    k_bfill<<<nbuk, 256, 0, stream>>>(gcur, gofs, bucketed, rowptr, dinv, csr_src, N);

    // 3. lin1 -> h0 (raw f16) + hs0 (scaled f16)
    k_lin1<<<(N + NBK - 1) / NBK, 256, 0, stream>>>(x, w1, b1, dinv, h0, hs0, N);

    // 4. three fused GCN2 layers: hs0 -> hb -> hs0 -> hb(raw)
    int nlb = (N + 15) / 16;
    float beta0 = logf(0.5f / 1.0f + 1.0f);
    float beta1 = logf(0.5f / 2.0f + 1.0f);
    float beta2 = logf(0.5f / 3.0f + 1.0f);
    k_layer<<<nlb, 256, 0, stream>>>(rowptr, csr_src, dinv, hs0, h0,
                                     convw + 0 * HID * HID, beta0, 1, hb, N);
    k_layer<<<nlb, 256, 0, stream>>>(rowptr, csr_src, dinv, hb, h0,
                                     convw + 1 * HID * HID, beta1, 1, hs0, N);
    k_layer<<<nlb, 256, 0, stream>>>(rowptr, csr_src, dinv, hs0, h0,
                                     convw + 2 * HID * HID, beta2, 0, hb, N);

    // 5. pooling + final linear (raw h is hb)
    hipMemsetAsync(psum, 0, ((size_t)NG * HID + NG) * 4, stream);
    k_pool<<<(N + POOL_CHUNK - 1) / POOL_CHUNK, 256, 0, stream>>>(hb, batch, flag,
                                                                  psum, pcnt, N);
    k_out<<<NG, 64, 0, stream>>>(psum, pcnt, w2, b2, out);
}

// Round 11
// 159.258 us; speedup vs baseline: 3.0571x; 1.1247x over previous
//
#include <hip/hip_runtime.h>
#include <hip/hip_fp16.h>
#include <math.h>

constexpr int IN_F = 128;
constexpr int HID  = 64;
constexpr int OUT_F = 10;
constexpr int NG   = 256;
constexpr int BSH  = 7;            // 128 nodes per bucket
constexpr int BNODES = 1 << BSH;
constexpr int CAP  = 3072;         // per-bucket edge capacity (mean ~2046)
constexpr int NBUK_MAX = 1024;     // supports N <= 131072
constexpr int EPB  = 8192;         // edges per bucket-sort block
constexpr int EMAX = 1024;         // LDS edge-stage capacity per layer block (mean ~256)

typedef _Float16 half8 __attribute__((ext_vector_type(8)));
typedef float f32x4 __attribute__((ext_vector_type(4)));

// ---- int32/int64 detection ----
__global__ void k_detect(const unsigned int* w, int nwords, int* flag) {
    __shared__ int nz;
    if (threadIdx.x == 0) nz = 0;
    __syncthreads();
    int seen = 0;
    for (int i = 1 + 2 * (int)threadIdx.x; i < nwords; i += 2 * (int)blockDim.x)
        if (w[i] != 0u) seen = 1;
    if (seen) atomicOr(&nz, 1);
    __syncthreads();
    if (threadIdx.x == 0) *flag = (nz == 0) ? 1 : 0;
}

__device__ __forceinline__ int ld_idx(const void* p, long long i, int is64) {
    return is64 ? (int)((const long long*)p)[i] : ((const int*)p)[i];
}

// ---- pass 1: block-level counting sort into contiguous per-bucket regions ----
__global__ __launch_bounds__(1024) void k_bucket2(const void* eidx, const int* f64,
                                                  int E, int nbuk,
                                                  int* gcur, unsigned* bucketed) {
    __shared__ int lhist[NBUK_MAX];
    __shared__ int lofs[NBUK_MAX];
    __shared__ int lcur[NBUK_MAX];
    __shared__ unsigned stage[EPB];
    __shared__ unsigned short sbid[EPB];
    int tid = threadIdx.x;
    long long base = (long long)blockIdx.x * EPB;
    int nval = (int)min((long long)EPB, (long long)E - base);
    int is64 = *f64;
    lhist[tid] = 0; lcur[tid] = 0;
    __syncthreads();
    unsigned pv[8]; int bv[8];
    #pragma unroll
    for (int j = 0; j < 8; ++j) {
        long long e = base + j * 1024 + tid;
        if (e < E) {
            int r = ld_idx(eidx, e, is64);
            int c = ld_idx(eidx, (long long)E + e, is64);
            int b = c >> BSH;
            pv[j] = (unsigned)r | ((unsigned)(c & (BNODES - 1)) << 20);
            bv[j] = b;
            atomicAdd(&lhist[b], 1);
        } else bv[j] = -1;
    }
    __syncthreads();
    lofs[tid] = lhist[tid];
    __syncthreads();
    for (int off = 1; off < NBUK_MAX; off <<= 1) {
        int v = (tid >= off) ? lofs[tid - off] : 0;
        __syncthreads();
        lofs[tid] += v;
        __syncthreads();
    }
    int cnt = lhist[tid];
    if (tid < nbuk && cnt > 0)
        lhist[tid] = atomicAdd(&gcur[tid], cnt);
    #pragma unroll
    for (int j = 0; j < 8; ++j) {
        if (bv[j] >= 0) {
            int b = bv[j];
            int ex = (b > 0) ? lofs[b - 1] : 0;
            int p = ex + atomicAdd(&lcur[b], 1);
            stage[p] = pv[j];
            sbid[p] = (unsigned short)b;
        }
    }
    __syncthreads();
    for (int p = tid; p < nval; p += 1024) {
        int b = sbid[p];
        int ex = (b > 0) ? lofs[b - 1] : 0;
        int dst = lhist[b] + (p - ex);
        if (dst < CAP)
            bucketed[(long long)b * CAP + dst] = stage[p];
    }
}

// ---- fallback for nbuk > NBUK_MAX ----
__global__ void k_bucket_fb(const void* eidx, const int* f64, int E,
                            int* gcur, unsigned* bucketed) {
    int e = blockIdx.x * blockDim.x + threadIdx.x;
    if (e >= E) return;
    int is64 = *f64;
    int r = ld_idx(eidx, e, is64);
    int c = ld_idx(eidx, (long long)E + e, is64);
    int b = c >> BSH;
    int pos = atomicAdd(&gcur[b], 1);
    if (pos < CAP)
        bucketed[(long long)b * CAP + pos] =
            (unsigned)r | ((unsigned)(c & (BNODES - 1)) << 20);
}

// ---- scan per-bucket totals -> bucket edge offsets ----
__global__ __launch_bounds__(512) void k_bscan(const int* __restrict__ gcur,
                                               int* __restrict__ gofs, int nbuk,
                                               int* rowptr, int N) {
    __shared__ int tot[512];
    int tid = threadIdx.x;
    int chunk = (nbuk + 511) / 512;
    int st = tid * chunk, en = min(st + chunk, nbuk);
    int s = 0;
    for (int i = st; i < en; ++i) s += min(gcur[i], CAP);
    tot[tid] = s;
    __syncthreads();
    for (int off = 1; off < 512; off <<= 1) {
        int a = (tid >= off) ? tot[tid - off] : 0;
        __syncthreads();
        tot[tid] += a;
        __syncthreads();
    }
    int run = tot[tid] - s;
    for (int i = st; i < en; ++i) { gofs[i] = run; run += min(gcur[i], CAP); }
    if (tid == 511) rowptr[N] = tot[511];
}

// ---- pass 2: per-bucket local counting sort -> rowptr, dinv, csr_src ----
__global__ __launch_bounds__(256) void k_bfill(const int* __restrict__ gcur,
                                               const int* __restrict__ gofs,
                                               const unsigned* __restrict__ bucketed,
                                               int* __restrict__ rowptr,
                                               float* __restrict__ dinv,
                                               int* __restrict__ csr_src, int N) {
    __shared__ int lhist[BNODES], lrp[BNODES], lcur[BNODES];
    __shared__ int stage[CAP];
    int b = blockIdx.x;
    int cnt = min(gcur[b], CAP);
    int base = gofs[b];
    int nb0 = b << BSH;
    int tid = threadIdx.x;
    const unsigned* bk = bucketed + (long long)b * CAP;
    if (tid < BNODES) { lhist[tid] = 0; lcur[tid] = 0; }
    __syncthreads();
    for (int t = tid; t < cnt; t += 256) atomicAdd(&lhist[bk[t] >> 20], 1);
    __syncthreads();
    if (tid < BNODES) lrp[tid] = lhist[tid];
    __syncthreads();
    for (int off = 1; off < BNODES; off <<= 1) {
        int a = (tid < BNODES && tid >= off) ? lrp[tid - off] : 0;
        __syncthreads();
        if (tid < BNODES) lrp[tid] += a;
        __syncthreads();
    }
    if (tid < BNODES) {
        int ex = lrp[tid] - lhist[tid];
        lrp[tid] = ex;
        int node = nb0 + tid;
        if (node < N) {
            rowptr[node] = base + ex;
            dinv[node] = rsqrtf((float)lhist[tid] + 1.0f);
        }
    }
    __syncthreads();
    for (int t = tid; t < cnt; t += 256) {
        unsigned v = bk[t];
        int lc = v >> 20;
        int q = atomicAdd(&lcur[lc], 1);
        stage[lrp[lc] + q] = (int)(v & 0xFFFFFu);
    }
    __syncthreads();
    for (int t = tid; t < cnt; t += 256) csr_src[base + t] = stage[t];
}

// ---- lin1: h0 = relu(x@w1+b1) raw f16; hs0 = h0*dinv f16 ----
constexpr int NBK = 16;
__global__ __launch_bounds__(256) void k_lin1(const float* __restrict__ x,
                                              const float* __restrict__ w1,
                                              const float* __restrict__ b1,
                                              const float* __restrict__ dinv,
                                              unsigned short* __restrict__ h0,
                                              unsigned short* __restrict__ hs0, int N) {
    __shared__ float xs[NBK][IN_F];
    int nb0 = blockIdx.x * NBK;
    for (int t = threadIdx.x; t < NBK * (IN_F / 4); t += 256) {
        int n = t >> 5, k4 = t & 31;
        int gn = nb0 + n;
        float4 v = make_float4(0.f, 0.f, 0.f, 0.f);
        if (gn < N) v = ((const float4*)x)[(long long)gn * (IN_F / 4) + k4];
        *(float4*)&xs[n][k4 * 4] = v;
    }
    __syncthreads();
    int wv = threadIdx.x >> 6;
    int c  = threadIdx.x & 63;
    int n0 = wv * 4;
    float bias = b1[c];
    float a0 = bias, a1 = bias, a2 = bias, a3 = bias;
    #pragma unroll 4
    for (int k = 0; k < IN_F; k += 4) {
        float w_0 = w1[(k + 0) * HID + c];
        float w_1 = w1[(k + 1) * HID + c];
        float w_2 = w1[(k + 2) * HID + c];
        float w_3 = w1[(k + 3) * HID + c];
        float4 x0 = *(float4*)&xs[n0 + 0][k];
        float4 x1 = *(float4*)&xs[n0 + 1][k];
        float4 x2 = *(float4*)&xs[n0 + 2][k];
        float4 x3 = *(float4*)&xs[n0 + 3][k];
        a0 = fmaf(x0.x, w_0, a0); a0 = fmaf(x0.y, w_1, a0);
        a0 = fmaf(x0.z, w_2, a0); a0 = fmaf(x0.w, w_3, a0);
        a1 = fmaf(x1.x, w_0, a1); a1 = fmaf(x1.y, w_1, a1);
        a1 = fmaf(x1.z, w_2, a1); a1 = fmaf(x1.w, w_3, a1);
        a2 = fmaf(x2.x, w_0, a2); a2 = fmaf(x2.y, w_1, a2);
        a2 = fmaf(x2.z, w_2, a2); a2 = fmaf(x2.w, w_3, a2);
        a3 = fmaf(x3.x, w_0, a3); a3 = fmaf(x3.y, w_1, a3);
        a3 = fmaf(x3.z, w_2, a3); a3 = fmaf(x3.w, w_3, a3);
    }
    float acc[4] = {a0, a1, a2, a3};
    #pragma unroll
    for (int n = 0; n < 4; ++n) {
        int gn = nb0 + n0 + n;
        if (gn < N) {
            float r = fmaxf(acc[n], 0.f);
            __half hr = __float2half(r);
            __half hs = __float2half(r * dinv[gn]);
            h0 [(long long)gn * HID + c] = *(unsigned short*)&hr;
            hs0[(long long)gn * HID + c] = *(unsigned short*)&hs;
        }
    }
}

// ---- fused GCN2 layer v5: LDS edge-stage + 4-node-parallel gather + MFMA ----
// lane l: node j = l>>4, slot q = (l>>3)&1, octet m = l&7.
__global__ __launch_bounds__(256) void k_layer(const int* __restrict__ rowptr,
                                               const int* __restrict__ csr_src,
                                               const float* __restrict__ dinv,
                                               const unsigned short* __restrict__ hs_in,
                                               const unsigned short* __restrict__ h0,
                                               const float* __restrict__ W,
                                               float beta, int scale_out,
                                               unsigned short* __restrict__ h_out, int N) {
    __shared__ unsigned short s_lds[16][HID];    // f16 s, swizzled
    __shared__ unsigned short wt_lds[HID][HID];  // f16 W^T [n][k], swizzled
    __shared__ int ldsidx[EMAX];
    __shared__ int lrowp[17];
    int tid = threadIdx.x;
    int l = tid & 63, wv = tid >> 6;
    int nb = blockIdx.x * 16;

    // stage rowptr boundaries
    if (tid < 17) lrowp[tid] = rowptr[min(nb + tid, N)];
    // stage W^T (coalesced float4 reads; scalar swizzled LDS writes)
    #pragma unroll
    for (int jw = 0; jw < 4; ++jw) {
        int f = (jw * 256 + tid) * 4;              // element index, 4 at a time
        int k = f >> 6, n0 = f & 63;
        float4 wv4 = *(const float4*)&W[f];
        int slot = (k >> 3);
        int kk = k & 7;
        wt_lds[n0 + 0][((slot ^ ((n0 + 0) & 7)) * 8) + kk] = (unsigned short)__half_as_ushort(__float2half(wv4.x));
        wt_lds[n0 + 1][((slot ^ ((n0 + 1) & 7)) * 8) + kk] = (unsigned short)__half_as_ushort(__float2half(wv4.y));
        wt_lds[n0 + 2][((slot ^ ((n0 + 2) & 7)) * 8) + kk] = (unsigned short)__half_as_ushort(__float2half(wv4.z));
        wt_lds[n0 + 3][((slot ^ ((n0 + 3) & 7)) * 8) + kk] = (unsigned short)__half_as_ushort(__float2half(wv4.w));
    }
    __syncthreads();

    // stage block's contiguous edge window
    int eblk0 = lrowp[0];
    int ecnt = lrowp[16] - eblk0;
    bool use_lds = (ecnt <= EMAX);
    if (use_lds)
        for (int t = tid; t < ecnt; t += 256) ldsidx[t] = csr_src[eblk0 + t];
    __syncthreads();

    const uint4* hin4 = (const uint4*)hs_in;
    const uint4* h04  = (const uint4*)h0;
    int j = l >> 4, q = (l >> 3) & 1, m = l & 7;
    int row = wv * 4 + j;
    int node = nb + row;
    int e0 = lrowp[row], e1 = lrowp[row + 1];

    __half2 a[4] = {__half2(0.f, 0.f), __half2(0.f, 0.f),
                    __half2(0.f, 0.f), __half2(0.f, 0.f)};
    if (use_lds) {
        for (int e = e0 + q; e < e1; e += 2) {
            int r = ldsidx[e - eblk0];
            uint4 v = hin4[(long long)r * 8 + m];
            const __half2* p = (const __half2*)&v;
            #pragma unroll
            for (int jj = 0; jj < 4; ++jj) a[jj] = __hadd2(a[jj], p[jj]);
        }
    } else {
        for (int e = e0 + q; e < e1; e += 2) {
            int r = csr_src[e];
            uint4 v = hin4[(long long)r * 8 + m];
            const __half2* p = (const __half2*)&v;
            #pragma unroll
            for (int jj = 0; jj < 4; ++jj) a[jj] = __hadd2(a[jj], p[jj]);
        }
    }
    // fold the 2 slots within each node's 16-lane group
    #pragma unroll
    for (int jj = 0; jj < 4; ++jj) {
        unsigned t = __shfl_xor(*(unsigned*)&a[jj], 8, 64);
        a[jj] = __hadd2(a[jj], *(__half2*)&t);
    }
    if (q == 0) {   // 8 lanes per node finalize channels 8m..8m+7
        if (node < N) {
            float di = dinv[node];
            uint4 hv = hin4[(long long)node * 8 + m];
            uint4 rv = h04 [(long long)node * 8 + m];
            const __half2* hp = (const __half2*)&hv;
            const __half2* rp = (const __half2*)&rv;
            __attribute__((aligned(16))) unsigned short out8[8];
            #pragma unroll
            for (int jj = 0; jj < 4; ++jj) {
                __half2 t = __hadd2(a[jj], hp[jj]);
                float slo = fmaf(0.9f * di, __low2float(t),  0.1f * __low2float(rp[jj]));
                float shi = fmaf(0.9f * di, __high2float(t), 0.1f * __high2float(rp[jj]));
                *(__half2*)&out8[jj * 2] = __floats2half2_rn(slo, shi);
            }
            int slot = m ^ (row & 7);
            *(uint4*)&s_lds[row][slot * 8] = *(uint4*)out8;
        } else {
            int slot = m ^ (row & 7);
            uint4 z = make_uint4(0, 0, 0, 0);
            *(uint4*)&s_lds[row][slot * 8] = z;
        }
    }
    __syncthreads();

    // MFMA: wave wv computes output cols 16*wv .. 16*wv+15
    int i16 = l & 15, kc = l >> 4;
    f32x4 acc = {0.f, 0.f, 0.f, 0.f};
    #pragma unroll
    for (int ks = 0; ks < 2; ++ks) {
        int cb = ks * 4 + kc;
        int sa = cb ^ (i16 & 7);
        half8 av = *(half8*)&s_lds[i16][sa * 8];
        int n = wv * 16 + i16;
        int sb = cb ^ (n & 7);
        half8 bv = *(half8*)&wt_lds[n][sb * 8];
        acc = __builtin_amdgcn_mfma_f32_16x16x32_f16(av, bv, acc, 0, 0, 0);
    }
    #pragma unroll
    for (int r = 0; r < 4; ++r) {
        int orow = kc * 4 + r;
        int onode = nb + orow;
        if (onode < N) {
            int colg = wv * 16 + i16;
            int slot = (colg >> 3) ^ (orow & 7);
            __half sh = *(__half*)&s_lds[orow][slot * 8 + (colg & 7)];
            float sv = __half2float(sh);
            float v = fmaxf(sv + beta * (acc[r] - sv), 0.f);
            if (scale_out) v *= dinv[onode];
            __half hv2 = __float2half(v);
            h_out[(long long)onode * HID + colg] = *(unsigned short*)&hv2;
        }
    }
}

// ---- pooling ----
constexpr int POOL_CHUNK = 256;
__global__ __launch_bounds__(256) void k_pool(const unsigned short* __restrict__ h,
                                              const void* batch, const int* f64,
                                              float* psum, float* pcnt, int N) {
    int c = threadIdx.x & 63;
    int g = threadIdx.x >> 6;
    int n0 = blockIdx.x * POOL_CHUNK;
    int nend = min(n0 + POOL_CHUNK, N);
    int is64 = *f64;
    float sum = 0.f;
    int cnt = 0, curb = -1;
    for (int n = n0 + g; n < nend; n += 4) {
        int b = ld_idx(batch, n, is64);
        if (b != curb) {
            if (curb >= 0) {
                atomicAdd(&psum[(long long)curb * HID + c], sum);
                if (c == 0) atomicAdd(&pcnt[curb], (float)cnt);
            }
            curb = b; sum = 0.f; cnt = 0;
        }
        __half hv = *(__half*)&h[(long long)n * HID + c];
        sum += __half2float(hv);
        cnt++;
    }
    if (curb >= 0) {
        atomicAdd(&psum[(long long)curb * HID + c], sum);
        if (c == 0) atomicAdd(&pcnt[curb], (float)cnt);
    }
}

// ---- out[g] = (psum[g]/max(cnt,1)) @ w2 + b2 ----
__global__ void k_out(const float* __restrict__ psum, const float* __restrict__ pcnt,
                      const float* __restrict__ w2, const float* __restrict__ b2,
                      float* __restrict__ out) {
    int g = blockIdx.x;
    int tid = threadIdx.x;
    __shared__ float pr[HID];
    float cnt = fmaxf(pcnt[g], 1.0f);
    pr[tid] = psum[(long long)g * HID + tid] / cnt;
    __syncthreads();
    if (tid < OUT_F) {
        float acc = b2[tid];
        #pragma unroll
        for (int k = 0; k < HID; ++k)
            acc = fmaf(pr[k], w2[k * OUT_F + tid], acc);
        out[g * OUT_F + tid] = acc;
    }
}

static inline size_t align256(size_t x) { return (x + 255) & ~(size_t)255; }

extern "C" void kernel_launch(void* const* d_in, const int* in_sizes, int n_in,
                              void* d_out, int out_size, void* d_ws, size_t ws_size,
                              hipStream_t stream) {
    const float* x     = (const float*)d_in[0];
    const void*  eidx  = d_in[1];
    const void*  batch = d_in[2];
    const float* w1    = (const float*)d_in[3];
    const float* b1    = (const float*)d_in[4];
    const float* convw = (const float*)d_in[5];
    const float* w2    = (const float*)d_in[6];
    const float* b2    = (const float*)d_in[7];
    float* out = (float*)d_out;

    int N = in_sizes[0] / IN_F;
    int E = in_sizes[1] / 2;
    int nbuk = (N + BNODES - 1) >> BSH;

    char* ws = (char*)d_ws;
    float* dinv    = (float*)ws;                ws += align256((size_t)N * 4);
    unsigned short* h0  = (unsigned short*)ws;  ws += align256((size_t)N * HID * 2);
    unsigned short* hs0 = (unsigned short*)ws;  ws += align256((size_t)N * HID * 2);
    unsigned short* hb  = (unsigned short*)ws;  ws += align256((size_t)N * HID * 2);
    float* psum    = (float*)ws;                ws += align256((size_t)NG * HID * 4);
    float* pcnt    = (float*)ws;                ws += align256((size_t)NG * 4);
    int*   rowptr  = (int*)ws;                  ws += align256((size_t)(N + 1) * 4);
    int*   csr_src = (int*)ws;                  ws += align256((size_t)E * 4);
    int*   gcur    = (int*)ws;                  ws += align256((size_t)nbuk * 4);
    int*   gofs    = (int*)ws;                  ws += align256((size_t)(nbuk + 1) * 4);
    unsigned* bucketed = (unsigned*)ws;         ws += align256((size_t)nbuk * CAP * 4);
    int*   flag    = (int*)ws;

    // 1. dtype detect
    k_detect<<<1, 256, 0, stream>>>((const unsigned int*)eidx, 4096, flag);

    // 2. CSR build: block counting-sort -> scan -> per-bucket sort
    hipMemsetAsync(gcur, 0, (size_t)nbuk * 4, stream);
    if (nbuk <= NBUK_MAX)
        k_bucket2<<<(E + EPB - 1) / EPB, 1024, 0, stream>>>(eidx, flag, E, nbuk,
                                                            gcur, bucketed);
    else
        k_bucket_fb<<<(E + 255) / 256, 256, 0, stream>>>(eidx, flag, E, gcur, bucketed);
    k_bscan<<<1, 512, 0, stream>>>(gcur, gofs, nbuk, rowptr, N);
    k_bfill<<<nbuk, 256, 0, stream>>>(gcur, gofs, bucketed, rowptr, dinv, csr_src, N);

    // 3. lin1 -> h0 (raw f16) + hs0 (scaled f16)
    k_lin1<<<(N + NBK - 1) / NBK, 256, 0, stream>>>(x, w1, b1, dinv, h0, hs0, N);

    // 4. three fused GCN2 layers: hs0 -> hb -> hs0 -> hb(raw)
    int nlb = (N + 15) / 16;
    float beta0 = logf(0.5f / 1.0f + 1.0f);
    float beta1 = logf(0.5f / 2.0f + 1.0f);
    float beta2 = logf(0.5f / 3.0f + 1.0f);
    k_layer<<<nlb, 256, 0, stream>>>(rowptr, csr_src, dinv, hs0, h0,
                                     convw + 0 * HID * HID, beta0, 1, hb, N);
    k_layer<<<nlb, 256, 0, stream>>>(rowptr, csr_src, dinv, hb, h0,
                                     convw + 1 * HID * HID, beta1, 1, hs0, N);
    k_layer<<<nlb, 256, 0, stream>>>(rowptr, csr_src, dinv, hs0, h0,
                                     convw + 2 * HID * HID, beta2, 0, hb, N);

    // 5. pooling + final linear (raw h is hb)
    hipMemsetAsync(psum, 0, ((size_t)NG * HID + NG) * 4, stream);
    k_pool<<<(N + POOL_CHUNK - 1) / POOL_CHUNK, 256, 0, stream>>>(hb, batch, flag,
                                                                  psum, pcnt, N);
    k_out<<<NG, 64, 0, stream>>>(psum, pcnt, w2, b2, out);
}

// Round 12
// 141.589 us; speedup vs baseline: 3.4385x; 1.1248x over previous
//
#include <hip/hip_runtime.h>
#include <hip/hip_fp16.h>
#include <math.h>

constexpr int IN_F = 128;
constexpr int HID  = 64;
constexpr int OUT_F = 10;
constexpr int NG   = 256;
constexpr int BSH  = 7;            // 128 nodes per bucket
constexpr int BNODES = 1 << BSH;
constexpr int CAP  = 3072;         // per-bucket edge capacity (mean ~2046)
constexpr int NBUK_MAX = 1024;     // supports N <= 131072
constexpr int EPB  = 8192;         // edges per bucket-sort block
constexpr int EMAX = 1024;         // LDS edge-stage capacity per layer block

typedef _Float16 half8 __attribute__((ext_vector_type(8)));
typedef float f32x4 __attribute__((ext_vector_type(4)));

// ---- int32/int64 detection ----
__global__ void k_detect(const unsigned int* w, int nwords, int* flag) {
    __shared__ int nz;
    if (threadIdx.x == 0) nz = 0;
    __syncthreads();
    int seen = 0;
    for (int i = 1 + 2 * (int)threadIdx.x; i < nwords; i += 2 * (int)blockDim.x)
        if (w[i] != 0u) seen = 1;
    if (seen) atomicOr(&nz, 1);
    __syncthreads();
    if (threadIdx.x == 0) *flag = (nz == 0) ? 1 : 0;
}

__device__ __forceinline__ int ld_idx(const void* p, long long i, int is64) {
    return is64 ? (int)((const long long*)p)[i] : ((const int*)p)[i];
}

// ---- pass 1: block-level counting sort into contiguous per-bucket regions ----
__global__ __launch_bounds__(1024) void k_bucket2(const void* eidx, const int* f64,
                                                  int E, int nbuk,
                                                  int* gcur, unsigned* bucketed) {
    __shared__ int lhist[NBUK_MAX];
    __shared__ int lofs[NBUK_MAX];
    __shared__ int lcur[NBUK_MAX];
    __shared__ unsigned stage[EPB];
    __shared__ unsigned short sbid[EPB];
    int tid = threadIdx.x;
    long long base = (long long)blockIdx.x * EPB;
    int nval = (int)min((long long)EPB, (long long)E - base);
    int is64 = *f64;
    lhist[tid] = 0; lcur[tid] = 0;
    __syncthreads();
    unsigned pv[8]; int bv[8];
    #pragma unroll
    for (int j = 0; j < 8; ++j) {
        long long e = base + j * 1024 + tid;
        if (e < E) {
            int r = ld_idx(eidx, e, is64);
            int c = ld_idx(eidx, (long long)E + e, is64);
            int b = c >> BSH;
            pv[j] = (unsigned)r | ((unsigned)(c & (BNODES - 1)) << 20);
            bv[j] = b;
            atomicAdd(&lhist[b], 1);
        } else bv[j] = -1;
    }
    __syncthreads();
    lofs[tid] = lhist[tid];
    __syncthreads();
    for (int off = 1; off < NBUK_MAX; off <<= 1) {
        int v = (tid >= off) ? lofs[tid - off] : 0;
        __syncthreads();
        lofs[tid] += v;
        __syncthreads();
    }
    int cnt = lhist[tid];
    if (tid < nbuk && cnt > 0)
        lhist[tid] = atomicAdd(&gcur[tid], cnt);
    #pragma unroll
    for (int j = 0; j < 8; ++j) {
        if (bv[j] >= 0) {
            int b = bv[j];
            int ex = (b > 0) ? lofs[b - 1] : 0;
            int p = ex + atomicAdd(&lcur[b], 1);
            stage[p] = pv[j];
            sbid[p] = (unsigned short)b;
        }
    }
    __syncthreads();
    for (int p = tid; p < nval; p += 1024) {
        int b = sbid[p];
        int ex = (b > 0) ? lofs[b - 1] : 0;
        int dst = lhist[b] + (p - ex);
        if (dst < CAP)
            bucketed[(long long)b * CAP + dst] = stage[p];
    }
}

// ---- fallback for nbuk > NBUK_MAX ----
__global__ void k_bucket_fb(const void* eidx, const int* f64, int E,
                            int* gcur, unsigned* bucketed) {
    int e = blockIdx.x * blockDim.x + threadIdx.x;
    if (e >= E) return;
    int is64 = *f64;
    int r = ld_idx(eidx, e, is64);
    int c = ld_idx(eidx, (long long)E + e, is64);
    int b = c >> BSH;
    int pos = atomicAdd(&gcur[b], 1);
    if (pos < CAP)
        bucketed[(long long)b * CAP + pos] =
            (unsigned)r | ((unsigned)(c & (BNODES - 1)) << 20);
}

// ---- scan per-bucket totals -> bucket edge offsets ----
__global__ __launch_bounds__(512) void k_bscan(const int* __restrict__ gcur,
                                               int* __restrict__ gofs, int nbuk,
                                               int* rowptr, int N) {
    __shared__ int tot[512];
    int tid = threadIdx.x;
    int chunk = (nbuk + 511) / 512;
    int st = tid * chunk, en = min(st + chunk, nbuk);
    int s = 0;
    for (int i = st; i < en; ++i) s += min(gcur[i], CAP);
    tot[tid] = s;
    __syncthreads();
    for (int off = 1; off < 512; off <<= 1) {
        int a = (tid >= off) ? tot[tid - off] : 0;
        __syncthreads();
        tot[tid] += a;
        __syncthreads();
    }
    int run = tot[tid] - s;
    for (int i = st; i < en; ++i) { gofs[i] = run; run += min(gcur[i], CAP); }
    if (tid == 511) rowptr[N] = tot[511];
}

// ---- pass 2: per-bucket local counting sort -> rowptr, dinv, csr_src ----
__global__ __launch_bounds__(256) void k_bfill(const int* __restrict__ gcur,
                                               const int* __restrict__ gofs,
                                               const unsigned* __restrict__ bucketed,
                                               int* __restrict__ rowptr,
                                               float* __restrict__ dinv,
                                               int* __restrict__ csr_src, int N) {
    __shared__ int lhist[BNODES], lrp[BNODES], lcur[BNODES];
    __shared__ int stage[CAP];
    int b = blockIdx.x;
    int cnt = min(gcur[b], CAP);
    int base = gofs[b];
    int nb0 = b << BSH;
    int tid = threadIdx.x;
    const unsigned* bk = bucketed + (long long)b * CAP;
    if (tid < BNODES) { lhist[tid] = 0; lcur[tid] = 0; }
    __syncthreads();
    for (int t = tid; t < cnt; t += 256) atomicAdd(&lhist[bk[t] >> 20], 1);
    __syncthreads();
    if (tid < BNODES) lrp[tid] = lhist[tid];
    __syncthreads();
    for (int off = 1; off < BNODES; off <<= 1) {
        int a = (tid < BNODES && tid >= off) ? lrp[tid - off] : 0;
        __syncthreads();
        if (tid < BNODES) lrp[tid] += a;
        __syncthreads();
    }
    if (tid < BNODES) {
        int ex = lrp[tid] - lhist[tid];
        lrp[tid] = ex;
        int node = nb0 + tid;
        if (node < N) {
            rowptr[node] = base + ex;
            dinv[node] = rsqrtf((float)lhist[tid] + 1.0f);
        }
    }
    __syncthreads();
    for (int t = tid; t < cnt; t += 256) {
        unsigned v = bk[t];
        int lc = v >> 20;
        int q = atomicAdd(&lcur[lc], 1);
        stage[lrp[lc] + q] = (int)(v & 0xFFFFFu);
    }
    __syncthreads();
    for (int t = tid; t < cnt; t += 256) csr_src[base + t] = stage[t];
}

// ---- lin1 v2 (MFMA): h0 = relu(x@w1+b1) f16; hs0 = h0*dinv f16 ----
// block = 256 thr (4 waves) = 64 nodes; x-tile + W1^T staged f16 in LDS.
constexpr int LNB = 64;
__global__ __launch_bounds__(256) void k_lin1(const float* __restrict__ x,
                                              const float* __restrict__ w1,
                                              const float* __restrict__ b1,
                                              const float* __restrict__ dinv,
                                              unsigned short* __restrict__ h0,
                                              unsigned short* __restrict__ hs0, int N) {
    __shared__ unsigned short xs[LNB][IN_F];   // f16, slot = kc ^ (row&15)
    __shared__ unsigned short wt[HID][IN_F];   // f16 w1T[n][k], slot = kc ^ (n&15)
    int tid = threadIdx.x;
    int l = tid & 63, wv = tid >> 6;
    int nb0 = blockIdx.x * LNB;

    // stage w1 (coalesced float4 along n; scalar swizzled LDS writes)
    for (int t = tid; t < (IN_F * HID / 4); t += 256) {
        int k = t >> 4;              // (t*4)/64
        int n0 = (t & 15) * 4;
        float4 v = *(const float4*)&w1[k * HID + n0];
        int kc = k >> 3, ke = k & 7;
        wt[n0 + 0][((kc ^ ((n0 + 0) & 15)) * 8) + ke] = __half_as_ushort(__float2half(v.x));
        wt[n0 + 1][((kc ^ ((n0 + 1) & 15)) * 8) + ke] = __half_as_ushort(__float2half(v.y));
        wt[n0 + 2][((kc ^ ((n0 + 2) & 15)) * 8) + ke] = __half_as_ushort(__float2half(v.z));
        wt[n0 + 3][((kc ^ ((n0 + 3) & 15)) * 8) + ke] = __half_as_ushort(__float2half(v.w));
    }
    // stage x-tile (8 f16 per thread-task = one 16B swizzled LDS write)
    for (int t = tid; t < LNB * (IN_F / 8); t += 256) {
        int row = t >> 4, kc = t & 15;
        int gn = nb0 + row;
        float4 va = make_float4(0.f, 0.f, 0.f, 0.f), vb = va;
        if (gn < N) {
            va = ((const float4*)x)[(long long)gn * 32 + kc * 2];
            vb = ((const float4*)x)[(long long)gn * 32 + kc * 2 + 1];
        }
        __attribute__((aligned(16))) unsigned short t8[8];
        t8[0] = __half_as_ushort(__float2half(va.x));
        t8[1] = __half_as_ushort(__float2half(va.y));
        t8[2] = __half_as_ushort(__float2half(va.z));
        t8[3] = __half_as_ushort(__float2half(va.w));
        t8[4] = __half_as_ushort(__float2half(vb.x));
        t8[5] = __half_as_ushort(__float2half(vb.y));
        t8[6] = __half_as_ushort(__float2half(vb.z));
        t8[7] = __half_as_ushort(__float2half(vb.w));
        int slot = kc ^ (row & 15);
        *(uint4*)&xs[row][slot * 8] = *(uint4*)t8;
    }
    __syncthreads();

    // wave wv: 16 nodes (rows wv*16..+15) x 64 cols via 4x4 mfma 16x16x32
    int i16 = l & 15, hk = l >> 4;
    f32x4 acc0 = {0.f,0.f,0.f,0.f}, acc1 = acc0, acc2 = acc0, acc3 = acc0;
    #pragma unroll
    for (int kc4 = 0; kc4 < 4; ++kc4) {
        int kc = kc4 * 4 + hk;
        int arow = wv * 16 + i16;
        half8 av = *(half8*)&xs[arow][(kc ^ (arow & 15)) * 8];
        half8 b0 = *(half8*)&wt[ 0 + i16][(kc ^ (( 0 + i16) & 15)) * 8];
        half8 b1v = *(half8*)&wt[16 + i16][(kc ^ ((16 + i16) & 15)) * 8];
        half8 b2v = *(half8*)&wt[32 + i16][(kc ^ ((32 + i16) & 15)) * 8];
        half8 b3v = *(half8*)&wt[48 + i16][(kc ^ ((48 + i16) & 15)) * 8];
        acc0 = __builtin_amdgcn_mfma_f32_16x16x32_f16(av, b0,  acc0, 0, 0, 0);
        acc1 = __builtin_amdgcn_mfma_f32_16x16x32_f16(av, b1v, acc1, 0, 0, 0);
        acc2 = __builtin_amdgcn_mfma_f32_16x16x32_f16(av, b2v, acc2, 0, 0, 0);
        acc3 = __builtin_amdgcn_mfma_f32_16x16x32_f16(av, b3v, acc3, 0, 0, 0);
    }
    // epilogue: C row = hk*4+r (within wave tile), col = ct*16+i16
    #pragma unroll
    for (int r = 0; r < 4; ++r) {
        int gn = nb0 + wv * 16 + hk * 4 + r;
        if (gn >= N) continue;
        float di = dinv[gn];
        float vr[4] = {acc0[r], acc1[r], acc2[r], acc3[r]};
        #pragma unroll
        for (int ct = 0; ct < 4; ++ct) {
            int col = ct * 16 + i16;
            float v = fmaxf(vr[ct] + b1[col], 0.f);
            h0 [(long long)gn * HID + col] = __half_as_ushort(__float2half(v));
            hs0[(long long)gn * HID + col] = __half_as_ushort(__float2half(v * di));
        }
    }
}

// ---- fused GCN2 layer v6: LDS edge-stage + 4-node-parallel 2-deep gather + MFMA ----
__global__ __launch_bounds__(256) void k_layer(const int* __restrict__ rowptr,
                                               const int* __restrict__ csr_src,
                                               const float* __restrict__ dinv,
                                               const unsigned short* __restrict__ hs_in,
                                               const unsigned short* __restrict__ h0,
                                               const float* __restrict__ W,
                                               float beta, int scale_out,
                                               unsigned short* __restrict__ h_out, int N) {
    __shared__ unsigned short s_lds[16][HID];
    __shared__ unsigned short wt_lds[HID][HID];
    __shared__ int ldsidx[EMAX];
    __shared__ int lrowp[17];
    int tid = threadIdx.x;
    int l = tid & 63, wv = tid >> 6;
    int nb = blockIdx.x * 16;

    if (tid < 17) lrowp[tid] = rowptr[min(nb + tid, N)];
    #pragma unroll
    for (int jw = 0; jw < 4; ++jw) {
        int f = (jw * 256 + tid) * 4;
        int k = f >> 6, n0 = f & 63;
        float4 wv4 = *(const float4*)&W[f];
        int slot = (k >> 3);
        int kk = k & 7;
        wt_lds[n0 + 0][((slot ^ ((n0 + 0) & 7)) * 8) + kk] = __half_as_ushort(__float2half(wv4.x));
        wt_lds[n0 + 1][((slot ^ ((n0 + 1) & 7)) * 8) + kk] = __half_as_ushort(__float2half(wv4.y));
        wt_lds[n0 + 2][((slot ^ ((n0 + 2) & 7)) * 8) + kk] = __half_as_ushort(__float2half(wv4.z));
        wt_lds[n0 + 3][((slot ^ ((n0 + 3) & 7)) * 8) + kk] = __half_as_ushort(__float2half(wv4.w));
    }
    __syncthreads();

    int eblk0 = lrowp[0];
    int ecnt = lrowp[16] - eblk0;
    bool use_lds = (ecnt <= EMAX);
    if (use_lds)
        for (int t = tid; t < ecnt; t += 256) ldsidx[t] = csr_src[eblk0 + t];
    __syncthreads();

    const uint4* hin4 = (const uint4*)hs_in;
    const uint4* h04  = (const uint4*)h0;
    int j = l >> 4, q = (l >> 3) & 1, m = l & 7;
    int row = wv * 4 + j;
    int node = nb + row;
    int e0 = lrowp[row], e1 = lrowp[row + 1];

    __half2 a[4] = {__half2(0.f, 0.f), __half2(0.f, 0.f),
                    __half2(0.f, 0.f), __half2(0.f, 0.f)};
    int e = e0 + q;
    if (use_lds) {
        for (; e + 2 < e1; e += 4) {           // 2-deep: e and e+2 in flight
            int r0 = ldsidx[e - eblk0];
            int r1 = ldsidx[e + 2 - eblk0];
            uint4 v0 = hin4[(long long)r0 * 8 + m];
            uint4 v1 = hin4[(long long)r1 * 8 + m];
            const __half2* p0 = (const __half2*)&v0;
            const __half2* p1 = (const __half2*)&v1;
            #pragma unroll
            for (int jj = 0; jj < 4; ++jj) a[jj] = __hadd2(a[jj], p0[jj]);
            #pragma unroll
            for (int jj = 0; jj < 4; ++jj) a[jj] = __hadd2(a[jj], p1[jj]);
        }
        if (e < e1) {
            uint4 v = hin4[(long long)ldsidx[e - eblk0] * 8 + m];
            const __half2* p = (const __half2*)&v;
            #pragma unroll
            for (int jj = 0; jj < 4; ++jj) a[jj] = __hadd2(a[jj], p[jj]);
        }
    } else {
        for (; e + 2 < e1; e += 4) {
            int r0 = csr_src[e];
            int r1 = csr_src[e + 2];
            uint4 v0 = hin4[(long long)r0 * 8 + m];
            uint4 v1 = hin4[(long long)r1 * 8 + m];
            const __half2* p0 = (const __half2*)&v0;
            const __half2* p1 = (const __half2*)&v1;
            #pragma unroll
            for (int jj = 0; jj < 4; ++jj) a[jj] = __hadd2(a[jj], p0[jj]);
            #pragma unroll
            for (int jj = 0; jj < 4; ++jj) a[jj] = __hadd2(a[jj], p1[jj]);
        }
        if (e < e1) {
            uint4 v = hin4[(long long)csr_src[e] * 8 + m];
            const __half2* p = (const __half2*)&v;
            #pragma unroll
            for (int jj = 0; jj < 4; ++jj) a[jj] = __hadd2(a[jj], p[jj]);
        }
    }
    #pragma unroll
    for (int jj = 0; jj < 4; ++jj) {
        unsigned t = __shfl_xor(*(unsigned*)&a[jj], 8, 64);
        a[jj] = __hadd2(a[jj], *(__half2*)&t);
    }
    if (q == 0) {
        if (node < N) {
            float di = dinv[node];
            uint4 hv = hin4[(long long)node * 8 + m];
            uint4 rv = h04 [(long long)node * 8 + m];
            const __half2* hp = (const __half2*)&hv;
            const __half2* rp = (const __half2*)&rv;
            __attribute__((aligned(16))) unsigned short out8[8];
            #pragma unroll
            for (int jj = 0; jj < 4; ++jj) {
                __half2 t = __hadd2(a[jj], hp[jj]);
                float slo = fmaf(0.9f * di, __low2float(t),  0.1f * __low2float(rp[jj]));
                float shi = fmaf(0.9f * di, __high2float(t), 0.1f * __high2float(rp[jj]));
                *(__half2*)&out8[jj * 2] = __floats2half2_rn(slo, shi);
            }
            int slot = m ^ (row & 7);
            *(uint4*)&s_lds[row][slot * 8] = *(uint4*)out8;
        } else {
            int slot = m ^ (row & 7);
            uint4 z = make_uint4(0, 0, 0, 0);
            *(uint4*)&s_lds[row][slot * 8] = z;
        }
    }
    __syncthreads();

    int i16 = l & 15, kc = l >> 4;
    f32x4 acc = {0.f, 0.f, 0.f, 0.f};
    #pragma unroll
    for (int ks = 0; ks < 2; ++ks) {
        int cb = ks * 4 + kc;
        int sa = cb ^ (i16 & 7);
        half8 av = *(half8*)&s_lds[i16][sa * 8];
        int n = wv * 16 + i16;
        int sb = cb ^ (n & 7);
        half8 bv = *(half8*)&wt_lds[n][sb * 8];
        acc = __builtin_amdgcn_mfma_f32_16x16x32_f16(av, bv, acc, 0, 0, 0);
    }
    #pragma unroll
    for (int r = 0; r < 4; ++r) {
        int orow = kc * 4 + r;
        int onode = nb + orow;
        if (onode < N) {
            int colg = wv * 16 + i16;
            int slot = (colg >> 3) ^ (orow & 7);
            __half sh = *(__half*)&s_lds[orow][slot * 8 + (colg & 7)];
            float sv = __half2float(sh);
            float v = fmaxf(sv + beta * (acc[r] - sv), 0.f);
            if (scale_out) v *= dinv[onode];
            __half hv2 = __float2half(v);
            h_out[(long long)onode * HID + colg] = *(unsigned short*)&hv2;
        }
    }
}

// ---- pooling ----
constexpr int POOL_CHUNK = 256;
__global__ __launch_bounds__(256) void k_pool(const unsigned short* __restrict__ h,
                                              const void* batch, const int* f64,
                                              float* psum, float* pcnt, int N) {
    int c = threadIdx.x & 63;
    int g = threadIdx.x >> 6;
    int n0 = blockIdx.x * POOL_CHUNK;
    int nend = min(n0 + POOL_CHUNK, N);
    int is64 = *f64;
    float sum = 0.f;
    int cnt = 0, curb = -1;
    for (int n = n0 + g; n < nend; n += 4) {
        int b = ld_idx(batch, n, is64);
        if (b != curb) {
            if (curb >= 0) {
                atomicAdd(&psum[(long long)curb * HID + c], sum);
                if (c == 0) atomicAdd(&pcnt[curb], (float)cnt);
            }
            curb = b; sum = 0.f; cnt = 0;
        }
        __half hv = *(__half*)&h[(long long)n * HID + c];
        sum += __half2float(hv);
        cnt++;
    }
    if (curb >= 0) {
        atomicAdd(&psum[(long long)curb * HID + c], sum);
        if (c == 0) atomicAdd(&pcnt[curb], (float)cnt);
    }
}

// ---- out[g] = (psum[g]/max(cnt,1)) @ w2 + b2 ----
__global__ void k_out(const float* __restrict__ psum, const float* __restrict__ pcnt,
                      const float* __restrict__ w2, const float* __restrict__ b2,
                      float* __restrict__ out) {
    int g = blockIdx.x;
    int tid = threadIdx.x;
    __shared__ float pr[HID];
    float cnt = fmaxf(pcnt[g], 1.0f);
    pr[tid] = psum[(long long)g * HID + tid] / cnt;
    __syncthreads();
    if (tid < OUT_F) {
        float acc = b2[tid];
        #pragma unroll
        for (int k = 0; k < HID; ++k)
            acc = fmaf(pr[k], w2[k * OUT_F + tid], acc);
        out[g * OUT_F + tid] = acc;
    }
}

static inline size_t align256(size_t x) { return (x + 255) & ~(size_t)255; }

extern "C" void kernel_launch(void* const* d_in, const int* in_sizes, int n_in,
                              void* d_out, int out_size, void* d_ws, size_t ws_size,
                              hipStream_t stream) {
    const float* x     = (const float*)d_in[0];
    const void*  eidx  = d_in[1];
    const void*  batch = d_in[2];
    const float* w1    = (const float*)d_in[3];
    const float* b1    = (const float*)d_in[4];
    const float* convw = (const float*)d_in[5];
    const float* w2    = (const float*)d_in[6];
    const float* b2    = (const float*)d_in[7];
    float* out = (float*)d_out;

    int N = in_sizes[0] / IN_F;
    int E = in_sizes[1] / 2;
    int nbuk = (N + BNODES - 1) >> BSH;

    char* ws = (char*)d_ws;
    float* dinv    = (float*)ws;                ws += align256((size_t)N * 4);
    unsigned short* h0  = (unsigned short*)ws;  ws += align256((size_t)N * HID * 2);
    unsigned short* hs0 = (unsigned short*)ws;  ws += align256((size_t)N * HID * 2);
    unsigned short* hb  = (unsigned short*)ws;  ws += align256((size_t)N * HID * 2);
    float* psum    = (float*)ws;                ws += align256((size_t)NG * HID * 4);
    float* pcnt    = (float*)ws;                ws += align256((size_t)NG * 4);
    int*   rowptr  = (int*)ws;                  ws += align256((size_t)(N + 1) * 4);
    int*   csr_src = (int*)ws;                  ws += align256((size_t)E * 4);
    int*   gcur    = (int*)ws;                  ws += align256((size_t)nbuk * 4);
    int*   gofs    = (int*)ws;                  ws += align256((size_t)(nbuk + 1) * 4);
    unsigned* bucketed = (unsigned*)ws;         ws += align256((size_t)nbuk * CAP * 4);
    int*   flag    = (int*)ws;

    // 1. dtype detect
    k_detect<<<1, 256, 0, stream>>>((const unsigned int*)eidx, 4096, flag);

    // 2. CSR build: block counting-sort -> scan -> per-bucket sort
    hipMemsetAsync(gcur, 0, (size_t)nbuk * 4, stream);
    if (nbuk <= NBUK_MAX)
        k_bucket2<<<(E + EPB - 1) / EPB, 1024, 0, stream>>>(eidx, flag, E, nbuk,
                                                            gcur, bucketed);
    else
        k_bucket_fb<<<(E + 255) / 256, 256, 0, stream>>>(eidx, flag, E, gcur, bucketed);
    k_bscan<<<1, 512, 0, stream>>>(gcur, gofs, nbuk, rowptr, N);
    k_bfill<<<nbuk, 256, 0, stream>>>(gcur, gofs, bucketed, rowptr, dinv, csr_src, N);

    // 3. lin1 (MFMA) -> h0 (raw f16) + hs0 (scaled f16)
    k_lin1<<<(N + LNB - 1) / LNB, 256, 0, stream>>>(x, w1, b1, dinv, h0, hs0, N);

    // 4. three fused GCN2 layers: hs0 -> hb -> hs0 -> hb(raw)
    int nlb = (N + 15) / 16;
    float beta0 = logf(0.5f / 1.0f + 1.0f);
    float beta1 = logf(0.5f / 2.0f + 1.0f);
    float beta2 = logf(0.5f / 3.0f + 1.0f);
    k_layer<<<nlb, 256, 0, stream>>>(rowptr, csr_src, dinv, hs0, h0,
                                     convw + 0 * HID * HID, beta0, 1, hb, N);
    k_layer<<<nlb, 256, 0, stream>>>(rowptr, csr_src, dinv, hb, h0,
                                     convw + 1 * HID * HID, beta1, 1, hs0, N);
    k_layer<<<nlb, 256, 0, stream>>>(rowptr, csr_src, dinv, hs0, h0,
                                     convw + 2 * HID * HID, beta2, 0, hb, N);

    // 5. pooling + final linear (raw h is hb)
    hipMemsetAsync(psum, 0, ((size_t)NG * HID + NG) * 4, stream);
    k_pool<<<(N + POOL_CHUNK - 1) / POOL_CHUNK, 256, 0, stream>>>(hb, batch, flag,
                                                                  psum, pcnt, N);
    k_out<<<NG, 64, 0, stream>>>(psum, pcnt, w2, b2, out);
}

// Round 13
// 135.331 us; speedup vs baseline: 3.5976x; 1.0462x over previous
//
#include <hip/hip_runtime.h>
#include <hip/hip_fp16.h>
#include <math.h>

constexpr int IN_F = 128;
constexpr int HID  = 64;
constexpr int OUT_F = 10;
constexpr int NG   = 256;
constexpr int BSH  = 7;            // 128 nodes per bucket
constexpr int BNODES = 1 << BSH;
constexpr int CAP  = 3072;         // per-bucket edge capacity (mean ~2046)
constexpr int NBUK_MAX = 1024;     // supports N <= 131072
constexpr int EPB  = 8192;         // edges per bucket-sort block
constexpr int EMAX = 1024;         // LDS edge-stage capacity per layer block

typedef _Float16 half8 __attribute__((ext_vector_type(8)));
typedef float f32x4 __attribute__((ext_vector_type(4)));

// ---- int32/int64 detection + gcur zeroing ----
__global__ void k_detect(const unsigned int* w, int nwords, int* flag,
                         int* gcur, int nbuk) {
    __shared__ int nz;
    if (threadIdx.x == 0) nz = 0;
    for (int t = threadIdx.x; t < nbuk; t += 256) gcur[t] = 0;
    __syncthreads();
    int seen = 0;
    for (int i = 1 + 2 * (int)threadIdx.x; i < nwords; i += 2 * (int)blockDim.x)
        if (w[i] != 0u) seen = 1;
    if (seen) atomicOr(&nz, 1);
    __syncthreads();
    if (threadIdx.x == 0) *flag = (nz == 0) ? 1 : 0;
}

__device__ __forceinline__ int ld_idx(const void* p, long long i, int is64) {
    return is64 ? (int)((const long long*)p)[i] : ((const int*)p)[i];
}

// ---- pass 1: block-level counting sort into contiguous per-bucket regions ----
__global__ __launch_bounds__(1024) void k_bucket2(const void* eidx, const int* f64,
                                                  int E, int nbuk,
                                                  int* gcur, unsigned* bucketed) {
    __shared__ int lhist[NBUK_MAX];
    __shared__ int lofs[NBUK_MAX];
    __shared__ int lcur[NBUK_MAX];
    __shared__ unsigned stage[EPB];
    __shared__ unsigned short sbid[EPB];
    int tid = threadIdx.x;
    long long base = (long long)blockIdx.x * EPB;
    int nval = (int)min((long long)EPB, (long long)E - base);
    int is64 = *f64;
    lhist[tid] = 0; lcur[tid] = 0;
    __syncthreads();
    unsigned pv[8]; int bv[8];
    #pragma unroll
    for (int j = 0; j < 8; ++j) {
        long long e = base + j * 1024 + tid;
        if (e < E) {
            int r = ld_idx(eidx, e, is64);
            int c = ld_idx(eidx, (long long)E + e, is64);
            int b = c >> BSH;
            pv[j] = (unsigned)r | ((unsigned)(c & (BNODES - 1)) << 20);
            bv[j] = b;
            atomicAdd(&lhist[b], 1);
        } else bv[j] = -1;
    }
    __syncthreads();
    lofs[tid] = lhist[tid];
    __syncthreads();
    for (int off = 1; off < NBUK_MAX; off <<= 1) {
        int v = (tid >= off) ? lofs[tid - off] : 0;
        __syncthreads();
        lofs[tid] += v;
        __syncthreads();
    }
    int cnt = lhist[tid];
    if (tid < nbuk && cnt > 0)
        lhist[tid] = atomicAdd(&gcur[tid], cnt);
    #pragma unroll
    for (int j = 0; j < 8; ++j) {
        if (bv[j] >= 0) {
            int b = bv[j];
            int ex = (b > 0) ? lofs[b - 1] : 0;
            int p = ex + atomicAdd(&lcur[b], 1);
            stage[p] = pv[j];
            sbid[p] = (unsigned short)b;
        }
    }
    __syncthreads();
    for (int p = tid; p < nval; p += 1024) {
        int b = sbid[p];
        int ex = (b > 0) ? lofs[b - 1] : 0;
        int dst = lhist[b] + (p - ex);
        if (dst < CAP)
            bucketed[(long long)b * CAP + dst] = stage[p];
    }
}

// ---- fallback for nbuk > NBUK_MAX ----
__global__ void k_bucket_fb(const void* eidx, const int* f64, int E,
                            int* gcur, unsigned* bucketed) {
    int e = blockIdx.x * blockDim.x + threadIdx.x;
    if (e >= E) return;
    int is64 = *f64;
    int r = ld_idx(eidx, e, is64);
    int c = ld_idx(eidx, (long long)E + e, is64);
    int b = c >> BSH;
    int pos = atomicAdd(&gcur[b], 1);
    if (pos < CAP)
        bucketed[(long long)b * CAP + pos] =
            (unsigned)r | ((unsigned)(c & (BNODES - 1)) << 20);
}

// ---- scan per-bucket totals -> bucket edge offsets (+ psum/pcnt zeroing) ----
__global__ __launch_bounds__(512) void k_bscan(const int* __restrict__ gcur,
                                               int* __restrict__ gofs, int nbuk,
                                               int* rowptr, int N,
                                               float* psum, float* pcnt) {
    int tid = threadIdx.x;
    for (int t = tid; t < NG * HID; t += 512) psum[t] = 0.f;
    for (int t = tid; t < NG; t += 512) pcnt[t] = 0.f;
    __shared__ int tot[512];
    int chunk = (nbuk + 511) / 512;
    int st = tid * chunk, en = min(st + chunk, nbuk);
    int s = 0;
    for (int i = st; i < en; ++i) s += min(gcur[i], CAP);
    tot[tid] = s;
    __syncthreads();
    for (int off = 1; off < 512; off <<= 1) {
        int a = (tid >= off) ? tot[tid - off] : 0;
        __syncthreads();
        tot[tid] += a;
        __syncthreads();
    }
    int run = tot[tid] - s;
    for (int i = st; i < en; ++i) { gofs[i] = run; run += min(gcur[i], CAP); }
    if (tid == 511) rowptr[N] = tot[511];
}

// ---- pass 2: per-bucket local counting sort -> rowptr, dinv, csr_src ----
__global__ __launch_bounds__(256) void k_bfill(const int* __restrict__ gcur,
                                               const int* __restrict__ gofs,
                                               const unsigned* __restrict__ bucketed,
                                               int* __restrict__ rowptr,
                                               float* __restrict__ dinv,
                                               int* __restrict__ csr_src, int N) {
    __shared__ int lhist[BNODES], lrp[BNODES], lcur[BNODES];
    __shared__ int stage[CAP];
    int b = blockIdx.x;
    int cnt = min(gcur[b], CAP);
    int base = gofs[b];
    int nb0 = b << BSH;
    int tid = threadIdx.x;
    const unsigned* bk = bucketed + (long long)b * CAP;
    if (tid < BNODES) { lhist[tid] = 0; lcur[tid] = 0; }
    __syncthreads();
    for (int t = tid; t < cnt; t += 256) atomicAdd(&lhist[bk[t] >> 20], 1);
    __syncthreads();
    if (tid < BNODES) lrp[tid] = lhist[tid];
    __syncthreads();
    for (int off = 1; off < BNODES; off <<= 1) {
        int a = (tid < BNODES && tid >= off) ? lrp[tid - off] : 0;
        __syncthreads();
        if (tid < BNODES) lrp[tid] += a;
        __syncthreads();
    }
    if (tid < BNODES) {
        int ex = lrp[tid] - lhist[tid];
        lrp[tid] = ex;
        int node = nb0 + tid;
        if (node < N) {
            rowptr[node] = base + ex;
            dinv[node] = rsqrtf((float)lhist[tid] + 1.0f);
        }
    }
    __syncthreads();
    for (int t = tid; t < cnt; t += 256) {
        unsigned v = bk[t];
        int lc = v >> 20;
        int q = atomicAdd(&lcur[lc], 1);
        stage[lrp[lc] + q] = (int)(v & 0xFFFFFu);
    }
    __syncthreads();
    for (int t = tid; t < cnt; t += 256) csr_src[base + t] = stage[t];
}

// ---- lin1 (MFMA): h0 = relu(x@w1+b1) f16; hs0 = h0*dinv f16 ----
constexpr int LNB = 64;
__global__ __launch_bounds__(256) void k_lin1(const float* __restrict__ x,
                                              const float* __restrict__ w1,
                                              const float* __restrict__ b1,
                                              const float* __restrict__ dinv,
                                              unsigned short* __restrict__ h0,
                                              unsigned short* __restrict__ hs0, int N) {
    __shared__ unsigned short xs[LNB][IN_F];
    __shared__ unsigned short wt[HID][IN_F];
    int tid = threadIdx.x;
    int l = tid & 63, wv = tid >> 6;
    int nb0 = blockIdx.x * LNB;

    for (int t = tid; t < (IN_F * HID / 4); t += 256) {
        int k = t >> 4;
        int n0 = (t & 15) * 4;
        float4 v = *(const float4*)&w1[k * HID + n0];
        int kc = k >> 3, ke = k & 7;
        wt[n0 + 0][((kc ^ ((n0 + 0) & 15)) * 8) + ke] = __half_as_ushort(__float2half(v.x));
        wt[n0 + 1][((kc ^ ((n0 + 1) & 15)) * 8) + ke] = __half_as_ushort(__float2half(v.y));
        wt[n0 + 2][((kc ^ ((n0 + 2) & 15)) * 8) + ke] = __half_as_ushort(__float2half(v.z));
        wt[n0 + 3][((kc ^ ((n0 + 3) & 15)) * 8) + ke] = __half_as_ushort(__float2half(v.w));
    }
    for (int t = tid; t < LNB * (IN_F / 8); t += 256) {
        int row = t >> 4, kc = t & 15;
        int gn = nb0 + row;
        float4 va = make_float4(0.f, 0.f, 0.f, 0.f), vb = va;
        if (gn < N) {
            va = ((const float4*)x)[(long long)gn * 32 + kc * 2];
            vb = ((const float4*)x)[(long long)gn * 32 + kc * 2 + 1];
        }
        __attribute__((aligned(16))) unsigned short t8[8];
        t8[0] = __half_as_ushort(__float2half(va.x));
        t8[1] = __half_as_ushort(__float2half(va.y));
        t8[2] = __half_as_ushort(__float2half(va.z));
        t8[3] = __half_as_ushort(__float2half(va.w));
        t8[4] = __half_as_ushort(__float2half(vb.x));
        t8[5] = __half_as_ushort(__float2half(vb.y));
        t8[6] = __half_as_ushort(__float2half(vb.z));
        t8[7] = __half_as_ushort(__float2half(vb.w));
        int slot = kc ^ (row & 15);
        *(uint4*)&xs[row][slot * 8] = *(uint4*)t8;
    }
    __syncthreads();

    int i16 = l & 15, hk = l >> 4;
    f32x4 acc0 = {0.f,0.f,0.f,0.f}, acc1 = acc0, acc2 = acc0, acc3 = acc0;
    #pragma unroll
    for (int kc4 = 0; kc4 < 4; ++kc4) {
        int kc = kc4 * 4 + hk;
        int arow = wv * 16 + i16;
        half8 av = *(half8*)&xs[arow][(kc ^ (arow & 15)) * 8];
        half8 b0 = *(half8*)&wt[ 0 + i16][(kc ^ (( 0 + i16) & 15)) * 8];
        half8 b1v = *(half8*)&wt[16 + i16][(kc ^ ((16 + i16) & 15)) * 8];
        half8 b2v = *(half8*)&wt[32 + i16][(kc ^ ((32 + i16) & 15)) * 8];
        half8 b3v = *(half8*)&wt[48 + i16][(kc ^ ((48 + i16) & 15)) * 8];
        acc0 = __builtin_amdgcn_mfma_f32_16x16x32_f16(av, b0,  acc0, 0, 0, 0);
        acc1 = __builtin_amdgcn_mfma_f32_16x16x32_f16(av, b1v, acc1, 0, 0, 0);
        acc2 = __builtin_amdgcn_mfma_f32_16x16x32_f16(av, b2v, acc2, 0, 0, 0);
        acc3 = __builtin_amdgcn_mfma_f32_16x16x32_f16(av, b3v, acc3, 0, 0, 0);
    }
    #pragma unroll
    for (int r = 0; r < 4; ++r) {
        int gn = nb0 + wv * 16 + hk * 4 + r;
        if (gn >= N) continue;
        float di = dinv[gn];
        float vr[4] = {acc0[r], acc1[r], acc2[r], acc3[r]};
        #pragma unroll
        for (int ct = 0; ct < 4; ++ct) {
            int col = ct * 16 + i16;
            float v = fmaxf(vr[ct] + b1[col], 0.f);
            h0 [(long long)gn * HID + col] = __half_as_ushort(__float2half(v));
            hs0[(long long)gn * HID + col] = __half_as_ushort(__float2half(v * di));
        }
    }
}

// ---- fused GCN2 layer v7: LDS edge-stage + 4-node-parallel 4-deep gather + MFMA ----
__global__ __launch_bounds__(256) void k_layer(const int* __restrict__ rowptr,
                                               const int* __restrict__ csr_src,
                                               const float* __restrict__ dinv,
                                               const unsigned short* __restrict__ hs_in,
                                               const unsigned short* __restrict__ h0,
                                               const float* __restrict__ W,
                                               float beta, int scale_out,
                                               unsigned short* __restrict__ h_out, int N) {
    __shared__ unsigned short s_lds[16][HID];
    __shared__ unsigned short wt_lds[HID][HID];
    __shared__ int ldsidx[EMAX];
    __shared__ int lrowp[17];
    int tid = threadIdx.x;
    int l = tid & 63, wv = tid >> 6;
    int nb = blockIdx.x * 16;

    if (tid < 17) lrowp[tid] = rowptr[min(nb + tid, N)];
    #pragma unroll
    for (int jw = 0; jw < 4; ++jw) {
        int f = (jw * 256 + tid) * 4;
        int k = f >> 6, n0 = f & 63;
        float4 wv4 = *(const float4*)&W[f];
        int slot = (k >> 3);
        int kk = k & 7;
        wt_lds[n0 + 0][((slot ^ ((n0 + 0) & 7)) * 8) + kk] = __half_as_ushort(__float2half(wv4.x));
        wt_lds[n0 + 1][((slot ^ ((n0 + 1) & 7)) * 8) + kk] = __half_as_ushort(__float2half(wv4.y));
        wt_lds[n0 + 2][((slot ^ ((n0 + 2) & 7)) * 8) + kk] = __half_as_ushort(__float2half(wv4.z));
        wt_lds[n0 + 3][((slot ^ ((n0 + 3) & 7)) * 8) + kk] = __half_as_ushort(__float2half(wv4.w));
    }
    __syncthreads();

    int eblk0 = lrowp[0];
    int ecnt = lrowp[16] - eblk0;
    bool use_lds = (ecnt <= EMAX);
    if (use_lds)
        for (int t = tid; t < ecnt; t += 256) ldsidx[t] = csr_src[eblk0 + t];
    __syncthreads();

    const uint4* hin4 = (const uint4*)hs_in;
    const uint4* h04  = (const uint4*)h0;
    int j = l >> 4, q = (l >> 3) & 1, m = l & 7;
    int row = wv * 4 + j;
    int node = nb + row;
    int e0 = lrowp[row], e1 = lrowp[row + 1];

    __half2 a[4] = {__half2(0.f, 0.f), __half2(0.f, 0.f),
                    __half2(0.f, 0.f), __half2(0.f, 0.f)};
    __half2 b[4] = {__half2(0.f, 0.f), __half2(0.f, 0.f),
                    __half2(0.f, 0.f), __half2(0.f, 0.f)};
    int e = e0 + q;
    if (use_lds) {
        const int* lx = ldsidx - eblk0;
        for (; e + 6 < e1; e += 8) {           // 4-deep: e, e+2, e+4, e+6 in flight
            int r0 = lx[e], r1 = lx[e + 2], r2 = lx[e + 4], r3 = lx[e + 6];
            uint4 v0 = hin4[(long long)r0 * 8 + m];
            uint4 v1 = hin4[(long long)r1 * 8 + m];
            uint4 v2 = hin4[(long long)r2 * 8 + m];
            uint4 v3 = hin4[(long long)r3 * 8 + m];
            const __half2* p0 = (const __half2*)&v0;
            const __half2* p1 = (const __half2*)&v1;
            const __half2* p2 = (const __half2*)&v2;
            const __half2* p3 = (const __half2*)&v3;
            #pragma unroll
            for (int jj = 0; jj < 4; ++jj) {
                a[jj] = __hadd2(a[jj], p0[jj]);
                b[jj] = __hadd2(b[jj], p1[jj]);
            }
            #pragma unroll
            for (int jj = 0; jj < 4; ++jj) {
                a[jj] = __hadd2(a[jj], p2[jj]);
                b[jj] = __hadd2(b[jj], p3[jj]);
            }
        }
        for (; e < e1; e += 2) {
            uint4 v = hin4[(long long)lx[e] * 8 + m];
            const __half2* p = (const __half2*)&v;
            #pragma unroll
            for (int jj = 0; jj < 4; ++jj) a[jj] = __hadd2(a[jj], p[jj]);
        }
    } else {
        for (; e + 6 < e1; e += 8) {
            int r0 = csr_src[e], r1 = csr_src[e + 2];
            int r2 = csr_src[e + 4], r3 = csr_src[e + 6];
            uint4 v0 = hin4[(long long)r0 * 8 + m];
            uint4 v1 = hin4[(long long)r1 * 8 + m];
            uint4 v2 = hin4[(long long)r2 * 8 + m];
            uint4 v3 = hin4[(long long)r3 * 8 + m];
            const __half2* p0 = (const __half2*)&v0;
            const __half2* p1 = (const __half2*)&v1;
            const __half2* p2 = (const __half2*)&v2;
            const __half2* p3 = (const __half2*)&v3;
            #pragma unroll
            for (int jj = 0; jj < 4; ++jj) {
                a[jj] = __hadd2(a[jj], p0[jj]);
                b[jj] = __hadd2(b[jj], p1[jj]);
            }
            #pragma unroll
            for (int jj = 0; jj < 4; ++jj) {
                a[jj] = __hadd2(a[jj], p2[jj]);
                b[jj] = __hadd2(b[jj], p3[jj]);
            }
        }
        for (; e < e1; e += 2) {
            uint4 v = hin4[(long long)csr_src[e] * 8 + m];
            const __half2* p = (const __half2*)&v;
            #pragma unroll
            for (int jj = 0; jj < 4; ++jj) a[jj] = __hadd2(a[jj], p[jj]);
        }
    }
    #pragma unroll
    for (int jj = 0; jj < 4; ++jj) a[jj] = __hadd2(a[jj], b[jj]);
    #pragma unroll
    for (int jj = 0; jj < 4; ++jj) {
        unsigned t = __shfl_xor(*(unsigned*)&a[jj], 8, 64);
        a[jj] = __hadd2(a[jj], *(__half2*)&t);
    }
    if (q == 0) {
        if (node < N) {
            float di = dinv[node];
            uint4 hv = hin4[(long long)node * 8 + m];
            uint4 rv = h04 [(long long)node * 8 + m];
            const __half2* hp = (const __half2*)&hv;
            const __half2* rp = (const __half2*)&rv;
            __attribute__((aligned(16))) unsigned short out8[8];
            #pragma unroll
            for (int jj = 0; jj < 4; ++jj) {
                __half2 t = __hadd2(a[jj], hp[jj]);
                float slo = fmaf(0.9f * di, __low2float(t),  0.1f * __low2float(rp[jj]));
                float shi = fmaf(0.9f * di, __high2float(t), 0.1f * __high2float(rp[jj]));
                *(__half2*)&out8[jj * 2] = __floats2half2_rn(slo, shi);
            }
            int slot = m ^ (row & 7);
            *(uint4*)&s_lds[row][slot * 8] = *(uint4*)out8;
        } else {
            int slot = m ^ (row & 7);
            uint4 z = make_uint4(0, 0, 0, 0);
            *(uint4*)&s_lds[row][slot * 8] = z;
        }
    }
    __syncthreads();

    int i16 = l & 15, kc = l >> 4;
    f32x4 acc = {0.f, 0.f, 0.f, 0.f};
    #pragma unroll
    for (int ks = 0; ks < 2; ++ks) {
        int cb = ks * 4 + kc;
        int sa = cb ^ (i16 & 7);
        half8 av = *(half8*)&s_lds[i16][sa * 8];
        int n = wv * 16 + i16;
        int sb = cb ^ (n & 7);
        half8 bv = *(half8*)&wt_lds[n][sb * 8];
        acc = __builtin_amdgcn_mfma_f32_16x16x32_f16(av, bv, acc, 0, 0, 0);
    }
    #pragma unroll
    for (int r = 0; r < 4; ++r) {
        int orow = kc * 4 + r;
        int onode = nb + orow;
        if (onode < N) {
            int colg = wv * 16 + i16;
            int slot = (colg >> 3) ^ (orow & 7);
            __half sh = *(__half*)&s_lds[orow][slot * 8 + (colg & 7)];
            float sv = __half2float(sh);
            float v = fmaxf(sv + beta * (acc[r] - sv), 0.f);
            if (scale_out) v *= dinv[onode];
            __half hv2 = __float2half(v);
            h_out[(long long)onode * HID + colg] = *(unsigned short*)&hv2;
        }
    }
}

// ---- pooling ----
constexpr int POOL_CHUNK = 256;
__global__ __launch_bounds__(256) void k_pool(const unsigned short* __restrict__ h,
                                              const void* batch, const int* f64,
                                              float* psum, float* pcnt, int N) {
    int c = threadIdx.x & 63;
    int g = threadIdx.x >> 6;
    int n0 = blockIdx.x * POOL_CHUNK;
    int nend = min(n0 + POOL_CHUNK, N);
    int is64 = *f64;
    float sum = 0.f;
    int cnt = 0, curb = -1;
    for (int n = n0 + g; n < nend; n += 4) {
        int b = ld_idx(batch, n, is64);
        if (b != curb) {
            if (curb >= 0) {
                atomicAdd(&psum[(long long)curb * HID + c], sum);
                if (c == 0) atomicAdd(&pcnt[curb], (float)cnt);
            }
            curb = b; sum = 0.f; cnt = 0;
        }
        __half hv = *(__half*)&h[(long long)n * HID + c];
        sum += __half2float(hv);
        cnt++;
    }
    if (curb >= 0) {
        atomicAdd(&psum[(long long)curb * HID + c], sum);
        if (c == 0) atomicAdd(&pcnt[curb], (float)cnt);
    }
}

// ---- out[g] = (psum[g]/max(cnt,1)) @ w2 + b2 ----
__global__ void k_out(const float* __restrict__ psum, const float* __restrict__ pcnt,
                      const float* __restrict__ w2, const float* __restrict__ b2,
                      float* __restrict__ out) {
    int g = blockIdx.x;
    int tid = threadIdx.x;
    __shared__ float pr[HID];
    float cnt = fmaxf(pcnt[g], 1.0f);
    pr[tid] = psum[(long long)g * HID + tid] / cnt;
    __syncthreads();
    if (tid < OUT_F) {
        float acc = b2[tid];
        #pragma unroll
        for (int k = 0; k < HID; ++k)
            acc = fmaf(pr[k], w2[k * OUT_F + tid], acc);
        out[g * OUT_F + tid] = acc;
    }
}

static inline size_t align256(size_t x) { return (x + 255) & ~(size_t)255; }

extern "C" void kernel_launch(void* const* d_in, const int* in_sizes, int n_in,
                              void* d_out, int out_size, void* d_ws, size_t ws_size,
                              hipStream_t stream) {
    const float* x     = (const float*)d_in[0];
    const void*  eidx  = d_in[1];
    const void*  batch = d_in[2];
    const float* w1    = (const float*)d_in[3];
    const float* b1    = (const float*)d_in[4];
    const float* convw = (const float*)d_in[5];
    const float* w2    = (const float*)d_in[6];
    const float* b2    = (const float*)d_in[7];
    float* out = (float*)d_out;

    int N = in_sizes[0] / IN_F;
    int E = in_sizes[1] / 2;
    int nbuk = (N + BNODES - 1) >> BSH;

    char* ws = (char*)d_ws;
    float* dinv    = (float*)ws;                ws += align256((size_t)N * 4);
    unsigned short* h0  = (unsigned short*)ws;  ws += align256((size_t)N * HID * 2);
    unsigned short* hs0 = (unsigned short*)ws;  ws += align256((size_t)N * HID * 2);
    unsigned short* hb  = (unsigned short*)ws;  ws += align256((size_t)N * HID * 2);
    float* psum    = (float*)ws;                ws += align256((size_t)NG * HID * 4);
    float* pcnt    = (float*)ws;                ws += align256((size_t)NG * 4);
    int*   rowptr  = (int*)ws;                  ws += align256((size_t)(N + 1) * 4);
    int*   csr_src = (int*)ws;                  ws += align256((size_t)E * 4);
    int*   gcur    = (int*)ws;                  ws += align256((size_t)nbuk * 4);
    int*   gofs    = (int*)ws;                  ws += align256((size_t)(nbuk + 1) * 4);
    unsigned* bucketed = (unsigned*)ws;         ws += align256((size_t)nbuk * CAP * 4);
    int*   flag    = (int*)ws;

    // 1. dtype detect + gcur zeroing
    k_detect<<<1, 256, 0, stream>>>((const unsigned int*)eidx, 4096, flag, gcur, nbuk);

    // 2. CSR build: block counting-sort -> scan (+psum zero) -> per-bucket sort
    if (nbuk <= NBUK_MAX)
        k_bucket2<<<(E + EPB - 1) / EPB, 1024, 0, stream>>>(eidx, flag, E, nbuk,
                                                            gcur, bucketed);
    else
        k_bucket_fb<<<(E + 255) / 256, 256, 0, stream>>>(eidx, flag, E, gcur, bucketed);
    k_bscan<<<1, 512, 0, stream>>>(gcur, gofs, nbuk, rowptr, N, psum, pcnt);
    k_bfill<<<nbuk, 256, 0, stream>>>(gcur, gofs, bucketed, rowptr, dinv, csr_src, N);

    // 3. lin1 (MFMA) -> h0 (raw f16) + hs0 (scaled f16)
    k_lin1<<<(N + LNB - 1) / LNB, 256, 0, stream>>>(x, w1, b1, dinv, h0, hs0, N);

    // 4. three fused GCN2 layers: hs0 -> hb -> hs0 -> hb(raw)
    int nlb = (N + 15) / 16;
    float beta0 = logf(0.5f / 1.0f + 1.0f);
    float beta1 = logf(0.5f / 2.0f + 1.0f);
    float beta2 = logf(0.5f / 3.0f + 1.0f);
    k_layer<<<nlb, 256, 0, stream>>>(rowptr, csr_src, dinv, hs0, h0,
                                     convw + 0 * HID * HID, beta0, 1, hb, N);
    k_layer<<<nlb, 256, 0, stream>>>(rowptr, csr_src, dinv, hb, h0,
                                     convw + 1 * HID * HID, beta1, 1, hs0, N);
    k_layer<<<nlb, 256, 0, stream>>>(rowptr, csr_src, dinv, hs0, h0,
                                     convw + 2 * HID * HID, beta2, 0, hb, N);

    // 5. pooling + final linear (raw h is hb)
    k_pool<<<(N + POOL_CHUNK - 1) / POOL_CHUNK, 256, 0, stream>>>(hb, batch, flag,
                                                                  psum, pcnt, N);
    k_out<<<NG, 64, 0, stream>>>(psum, pcnt, w2, b2, out);
}